// Round 6
// baseline (209.213 us; speedup 1.0000x reference)
//
#include <hip/hip_runtime.h>

#define Bn 32
#define Wn 128
#define Sn 192
#define Dn 768
#define Hn 10
#define BHn 30
#define Cn 50
#define CAP 8
#define NEGV -1e30f
#define XPAD 4

__device__ __forceinline__ float fsig(float x) {
    return __builtin_amdgcn_rcpf(1.0f + __expf(-x));
}
__device__ __forceinline__ float ftanh(float x) {
    return 1.0f - 2.0f * __builtin_amdgcn_rcpf(1.0f + __expf(2.0f * x));
}
__device__ __forceinline__ float lane_bcast(float v, int srclane) {
    union { float f; int i; } u, w;
    u.f = v;
    w.i = __builtin_amdgcn_readlane(u.i, srclane);
    return w.f;
}
template <int Q>
__device__ __forceinline__ float quad_bcast(float v) {
    union { float f; int i; } u, w;
    u.f = v;
    w.i = __builtin_amdgcn_mov_dpp(u.i, (Q << 6) | (Q << 4) | (Q << 2) | Q, 0xf, 0xf, true);
    return w.f;
}

// ---------------- zero counters + output ----------------
__global__ void k_zero(int* cnt, float* out) {
    int i = blockIdx.x * blockDim.x + threadIdx.x;
    if (i < Bn * Wn) cnt[i] = 0;
    if (i == 0) out[0] = 0.f;
}

// ---------------- build token->word inverse lists ----------------
__global__ void k_lists(const int* __restrict__ b2t, int* cnt, int* lists) {
    int idx = blockIdx.x * blockDim.x + threadIdx.x;
    if (idx >= Bn * Sn) return;
    int b = idx / Sn;
    int w = b2t[idx];
    if (w < 0 || w >= Wn) return;
    int s = idx % Sn;
    int pos = atomicAdd(&cnt[b * Wn + w], 1);
    if (pos < CAP) lists[(b * Wn + w) * CAP + pos] = s;
}

// ---------------- token projection: tokg[b,s,dir,off] = (sum_l hid[l,b,s+1,:]) . Wih[row,:] ----------------
// (projection commutes with the segment-mean; bias and /(3*cnt) applied in k_wordmean)
__global__ __launch_bounds__(320) void k_tokproj(const float* __restrict__ hid,
                                                 const float* __restrict__ Wf,
                                                 const float* __restrict__ Wb,
                                                 float* __restrict__ tokg) {
    __shared__ float xl[16 * (Dn + XPAD)];
    int b = blockIdx.x / 12;
    int sc = blockIdx.x % 12;
    int s0 = sc * 16;
    // stage sum of 3 layers for 16 token rows
    for (int idx = threadIdx.x; idx < 16 * (Dn / 4); idx += 320) {
        int r = idx / (Dn / 4), k4 = idx % (Dn / 4);
        size_t rowbase = ((size_t)b * (Sn + 1) + (s0 + r + 1)) * Dn;
        const float4* p0 = (const float4*)(hid + rowbase) + k4;
        const float4* p1 = (const float4*)(hid + (size_t)Bn * (Sn + 1) * Dn + rowbase) + k4;
        const float4* p2 = (const float4*)(hid + (size_t)2 * Bn * (Sn + 1) * Dn + rowbase) + k4;
        float4 v0 = *p0, v1 = *p1, v2 = *p2;
        float4 v;
        v.x = v0.x + v1.x + v2.x; v.y = v0.y + v1.y + v2.y;
        v.z = v0.z + v1.z + v2.z; v.w = v0.w + v1.w + v2.w;
        ((float4*)(xl + r * (Dn + XPAD)))[k4] = v;
    }
    __syncthreads();

    int g = threadIdx.x >> 2;  // 0..79
    int tq = threadIdx.x & 3;  // 4 tokens each
    int dir = g / 40;
    int row = g % 40;          // gate*10 + j
    int off = (row % 10) * 4 + (row / 10); // j*4 + gate
    const float4* wrow = (const float4*)((dir ? Wb : Wf) + row * Dn);
    const float4* x0 = (const float4*)(xl + (tq * 4 + 0) * (Dn + XPAD));
    const float4* x1 = (const float4*)(xl + (tq * 4 + 1) * (Dn + XPAD));
    const float4* x2 = (const float4*)(xl + (tq * 4 + 2) * (Dn + XPAD));
    const float4* x3 = (const float4*)(xl + (tq * 4 + 3) * (Dn + XPAD));
    float a0 = 0.f, a1 = 0.f, a2 = 0.f, a3 = 0.f;
    for (int k = 0; k < Dn / 4; ++k) {
        float4 w = wrow[k];
        float4 v0 = x0[k], v1 = x1[k], v2 = x2[k], v3 = x3[k];
        a0 += w.x * v0.x + w.y * v0.y + w.z * v0.z + w.w * v0.w;
        a1 += w.x * v1.x + w.y * v1.y + w.z * v1.z + w.w * v1.w;
        a2 += w.x * v2.x + w.y * v2.y + w.z * v2.z + w.w * v2.w;
        a3 += w.x * v3.x + w.y * v3.y + w.z * v3.z + w.w * v3.w;
    }
    size_t base = ((size_t)b * Sn + s0 + tq * 4) * 2 + dir;
    tokg[(base + 0 * 2) * 40 + off] = a0;
    tokg[(base + 1 * 2) * 40 + off] = a1;
    tokg[(base + 2 * 2) * 40 + off] = a2;
    tokg[(base + 3 * 2) * 40 + off] = a3;
}

// ---------------- segment-mean in gate space + bias -> xg[(dir*Bn+b)*Wn+w][off] ----------------
__global__ __launch_bounds__(128) void k_wordmean(const float* __restrict__ tokg,
                                                  const int* __restrict__ cnt,
                                                  const int* __restrict__ lists,
                                                  const float* __restrict__ bih_f,
                                                  const float* __restrict__ bih_b,
                                                  float* __restrict__ xg) {
    int bw = blockIdx.x; // b*Wn + w
    int b = bw / Wn, w = bw % Wn;
    int l = threadIdx.x;
    if (l >= 80) return;
    int dir = l / 40, off = l % 40;
    int c = cnt[bw];
    int cc = c < CAP ? c : CAP;
    float acc = 0.f;
    for (int tk = 0; tk < cc; ++tk) {
        int s = lists[bw * CAP + tk];
        acc += tokg[(((size_t)b * Sn + s) * 2 + dir) * 40 + off];
    }
    float inv = 1.0f / (3.0f * (float)(c > 0 ? c : 1));
    int brow = (off & 3) * 10 + (off >> 2); // gate*10 + j
    float bias = (dir ? bih_b : bih_f)[brow];
    xg[((size_t)(dir * Bn + b) * Wn + w) * 40 + off] = acc * inv + bias;
}

// ---------------- LSTM scan: 1 seq/wave, readlane h-broadcast, DPP gate combine ----------------
__global__ __launch_bounds__(64) void k_lstm(const float* __restrict__ xg,
                                             const float* __restrict__ Whh_f, const float* __restrict__ bhh_f,
                                             const float* __restrict__ Whh_b, const float* __restrict__ bhh_b,
                                             float* __restrict__ hs) {
    int lane = threadIdx.x;
    int seq = blockIdx.x;      // 0..63
    int dir = seq >> 5;
    int l = lane < 40 ? lane : 39;
    int j = l >> 2, G = l & 3;

    const float* Whh = dir ? Whh_b : Whh_f;
    const float* bhh = dir ? bhh_b : bhh_f;
    float wk[Hn];
#pragma unroll
    for (int k = 0; k < Hn; ++k) wk[k] = Whh[(G * Hn + j) * Hn + k];
    float bias = bhh[G * Hn + j];

    const float* xbase = xg + (size_t)seq * Wn * 40; // layout [t][j*4+gate]
    float* hbase = hs + (size_t)seq * Wn * Hn;
    bool st = (G == 0) && (lane < 40);

    float h = 0.f, c = 0.f;
    int dt = dir ? -1 : 1;
    int t = dir ? (Wn - 1) : 0;
    float xq[4];
    xq[0] = xbase[t * 40 + l];
    xq[1] = xbase[(t + dt) * 40 + l];
    xq[2] = xbase[(t + 2 * dt) * 40 + l];

#pragma unroll 4
    for (int step = 0; step < Wn; ++step) {
        float xv = xq[step & 3];
        xq[(step + 3) & 3] = xbase[(t + 3 * dt) * 40 + l]; // prefetch 3 ahead
        // broadcast h vector from lanes 0,4,...,36 (VALU readlane, no LDS pipe)
        float hb[Hn];
#pragma unroll
        for (int k = 0; k < Hn; ++k) hb[k] = lane_bcast(h, 4 * k);
        // two parallel 5-FMA chains to halve the dependent-FMA depth
        float ga = xv, gb = bias;
#pragma unroll
        for (int k = 0; k < 5; ++k) ga += wk[k] * hb[k];
#pragma unroll
        for (int k = 5; k < Hn; ++k) gb += wk[k] * hb[k];
        float g = ga + gb;
        float gin = (G == 2) ? 2.f * g : g;
        float s = fsig(gin);
        float av = (G == 2) ? 2.f * s - 1.f : s;
        float ai = quad_bcast<0>(av);
        float af = quad_bcast<1>(av);
        float ag = quad_bcast<2>(av);
        float ao = quad_bcast<3>(av);
        c = af * c + ai * ag;
        h = ao * ftanh(c);
        if (st) hbase[t * Hn + j] = h;
        t += dt;
    }
}

// ---------------- MLP heads: 4x relu(x@W+b) with appended 1; also writes padded dr-h1 ----------------
__global__ __launch_bounds__(128) void k_mlp(const float* __restrict__ hs,
                                             const float* __restrict__ uW1, const float* __restrict__ ub1,
                                             const float* __restrict__ uW2, const float* __restrict__ ub2,
                                             const float* __restrict__ dW1, const float* __restrict__ db1,
                                             const float* __restrict__ dW2, const float* __restrict__ db2,
                                             float* __restrict__ harr, float* __restrict__ h1g) {
    int bt = blockIdx.x; // b*Wn + t
    int b = bt / Wn, t = bt % Wn;
    __shared__ float x[20];
    int tid = threadIdx.x;
    if (tid < 20) {
        x[tid] = (tid < Hn) ? hs[((size_t)(0 * Bn + b) * Wn + t) * Hn + tid]
                            : hs[((size_t)(1 * Bn + b) * Wn + t) * Hn + (tid - Hn)];
    }
    __syncthreads();
    if (tid == 124) h1g[(size_t)bt * 32 + 31] = 0.f; // pad
    if (tid >= 124) return;
    int which = tid / 31, k = tid % 31;
    float v;
    if (k == 30) {
        v = 1.0f;
    } else {
        const float* Wm;
        const float* bv;
        if (which == 0) { Wm = uW1; bv = ub1; }
        else if (which == 1) { Wm = uW2; bv = ub2; }
        else if (which == 2) { Wm = dW1; bv = db1; }
        else { Wm = dW2; bv = db2; }
        float a = bv[k];
#pragma unroll
        for (int d = 0; d < 20; ++d) a += x[d] * Wm[d * BHn + k];
        v = a > 0.f ? a : 0.f;
    }
    harr[((size_t)which * Bn * Wn + bt) * 31 + k] = v;
    if (which == 2) h1g[(size_t)bt * 32 + k] = v;
}

// ---------------- gather dr-h2 rows at j=head into padded array ----------------
__global__ __launch_bounds__(256) void k_gather(const float* __restrict__ harr,
                                                const int* __restrict__ heads,
                                                float* __restrict__ h2g) {
    int idx = blockIdx.x * 256 + threadIdx.x; // n*8 + q
    int n = idx >> 3, q = idx & 7;
    int b = n >> 7;
    int jh = heads[n];
    if (jh < 0 || jh >= Wn) jh = 0;
    const float* src = harr + ((size_t)3 * Bn * Wn + b * Wn + jh) * 31;
    float4 v;
    float tmp[4];
#pragma unroll
    for (int e = 0; e < 4; ++e) {
        int k = q * 4 + e;
        tmp[e] = (k < 31) ? src[k] : 0.f;
    }
    v.x = tmp[0]; v.y = tmp[1]; v.z = tmp[2]; v.w = tmp[3];
    ((float4*)(h2g + (size_t)n * 32))[q] = v;
}

// ---------------- deprel scores: thread=(n,o), U broadcast from LDS, h1/h2 in regs ----------------
__global__ __launch_bounds__(256) void k_drscore(const float* __restrict__ h1g,
                                                 const float* __restrict__ h2g,
                                                 const float* __restrict__ U, const float* __restrict__ dbias,
                                                 float* __restrict__ sc) {
    int nc = blockIdx.x & 63;
    int oq = blockIdx.x >> 6; // 0..12
    __shared__ float Ul[4][992]; // row stride 32 per h (aligned b128)
    int tid = threadIdx.x;
    for (int idx = tid; idx < 4 * 992; idx += 256) {
        int o = idx / 992, r = idx - o * 992;
        int h = r >> 5, g = r & 31;
        int oo = oq * 4 + o; if (oo >= Cn) oo = Cn - 1;
        Ul[o][r] = (g < 31) ? U[(size_t)oo * 961 + h * 31 + g] : 0.f;
    }
    int w = tid >> 6, lane = tid & 63;
    int o = oq * 4 + w;
    int n = nc * 64 + lane;
    float h2r[32];
    {
        const float4* p = (const float4*)(h2g + (size_t)n * 32);
#pragma unroll
        for (int q = 0; q < 8; ++q) {
            float4 v = p[q];
            h2r[4 * q + 0] = v.x; h2r[4 * q + 1] = v.y;
            h2r[4 * q + 2] = v.z; h2r[4 * q + 3] = v.w;
        }
    }
    float h1r[32];
    {
        const float4* p = (const float4*)(h1g + (size_t)n * 32);
#pragma unroll
        for (int q = 0; q < 8; ++q) {
            float4 v = p[q];
            h1r[4 * q + 0] = v.x; h1r[4 * q + 1] = v.y;
            h1r[4 * q + 2] = v.z; h1r[4 * q + 3] = v.w;
        }
    }
    __syncthreads();
    const float* up = Ul[w];
    float acc = 0.f;
    for (int h = 0; h < 31; ++h) {
        float t = 0.f;
#pragma unroll
        for (int g = 0; g < 32; ++g) t += up[h * 32 + g] * h2r[g];
        acc += h1r[h] * t;
    }
    if (o < Cn) sc[(size_t)n * Cn + o] = acc + dbias[o];
}

// ---------------- fused losses: blocks [0,4064) = unlabeled CE, [4064,8160) = deprel CE ----------------
__global__ __launch_bounds__(64) void k_loss(const float* __restrict__ harr,
                                             const float* __restrict__ U0, const float* __restrict__ ubias,
                                             const float* __restrict__ sc,
                                             const int* __restrict__ heads,
                                             const unsigned char* __restrict__ masks,
                                             const int* __restrict__ dep_rels,
                                             float* __restrict__ out) {
    int bid = blockIdx.x;
    int l = threadIdx.x;
    if (bid >= Bn * (Wn - 1)) {
        // ---- deprel CE, one wave per n ----
        int n = bid - Bn * (Wn - 1);
        float v = (l < Cn) ? sc[(size_t)n * Cn + l] : NEGV;
        float m = v;
#pragma unroll
        for (int off = 1; off < 64; off <<= 1) m = fmaxf(m, __shfl_xor(m, off));
        float e = (l < Cn) ? __expf(v - m) : 0.f;
#pragma unroll
        for (int off = 1; off < 64; off <<= 1) e += __shfl_xor(e, off);
        float lse = m + __logf(e);
        int r = dep_rels[n]; // uniform per wave
        float vr = __shfl(v, r);
        if (l == 0 && r != 0 && r < Cn) atomicAdd(out, -(vr - lse));
        return;
    }
    // ---- unlabeled CE ----
    int b = bid / (Wn - 1);
    int i = 1 + bid % (Wn - 1);
    const float* h2a = harr + (size_t)Bn * Wn * 31;
    __shared__ float h2s[Wn * 31];
    __shared__ float U0l[964];
    __shared__ float tgl[31];
    const float4* src = (const float4*)(h2a + (size_t)b * Wn * 31);
    for (int idx = l; idx < Wn * 31 / 4; idx += 64) ((float4*)h2s)[idx] = src[idx];
    for (int idx = l; idx < 240; idx += 64) ((float4*)U0l)[idx] = ((const float4*)U0)[idx];
    if (l == 0) U0l[960] = U0[960];
    __syncthreads();
    if (l < 31) {
        const float* h1row = harr + ((size_t)b * Wn + i) * 31;
        float a = 0.f;
        for (int h = 0; h < 31; ++h) a += h1row[h] * U0l[h * 31 + l];
        tgl[l] = a;
    }
    __syncthreads();
    float ub = ubias[0];
    float s0 = ub, s1 = ub;
    const float* r0 = h2s + l * 31;
    const float* r1 = h2s + (l + 64) * 31;
#pragma unroll
    for (int g = 0; g < 31; ++g) {
        float tv = tgl[g];
        s0 += tv * r0[g];
        s1 += tv * r1[g];
    }
    if (l == i) s0 = NEGV;
    if (l + 64 == i) s1 = NEGV;
    float m = fmaxf(s0, s1);
#pragma unroll
    for (int off = 1; off < 64; off <<= 1) m = fmaxf(m, __shfl_xor(m, off));
    float e = __expf(s0 - m) + __expf(s1 - m);
#pragma unroll
    for (int off = 1; off < 64; off <<= 1) e += __shfl_xor(e, off);
    float lse = m + __logf(e);
    int head = heads[b * Wn + i]; // uniform
    float v = (head < 64) ? s0 : s1;
    float sh = __shfl(v, head & 63);
    if (l == 0 && !masks[b * Wn + i]) atomicAdd(out, -(sh - lse));
}

extern "C" void kernel_launch(void* const* d_in, const int* in_sizes, int n_in,
                              void* d_out, int out_size, void* d_ws, size_t ws_size,
                              hipStream_t stream) {
    const float* hiddens = (const float*)d_in[0];
    const int* b2t = (const int*)d_in[1];
    const int* heads = (const int*)d_in[2];
    const int* dep_rels = (const int*)d_in[3];
    const unsigned char* masks = (const unsigned char*)d_in[4];
    const float* Wih_f = (const float*)d_in[6];
    const float* Whh_f = (const float*)d_in[7];
    const float* bih_f = (const float*)d_in[8];
    const float* bhh_f = (const float*)d_in[9];
    const float* Wih_b = (const float*)d_in[10];
    const float* Whh_b = (const float*)d_in[11];
    const float* bih_b = (const float*)d_in[12];
    const float* bhh_b = (const float*)d_in[13];
    const float* un_W1 = (const float*)d_in[14];
    const float* un_b1 = (const float*)d_in[15];
    const float* un_W2 = (const float*)d_in[16];
    const float* un_b2 = (const float*)d_in[17];
    const float* un_U  = (const float*)d_in[18];
    const float* un_bias = (const float*)d_in[19];
    const float* dr_W1 = (const float*)d_in[20];
    const float* dr_b1 = (const float*)d_in[21];
    const float* dr_W2 = (const float*)d_in[22];
    const float* dr_b2 = (const float*)d_in[23];
    const float* dr_U  = (const float*)d_in[24];
    const float* dr_bias = (const float*)d_in[25];

    char* p = (char*)d_ws;
    int* cnt = (int*)p;           p += (size_t)Bn * Wn * 4;
    int* lists = (int*)p;         p += (size_t)Bn * Wn * CAP * 4;
    float* tokg = (float*)p;      p += (size_t)Bn * Sn * 80 * 4;
    float* xg = (float*)p;        p += (size_t)2 * Bn * Wn * 40 * 4;
    float* hs = (float*)p;        p += (size_t)2 * Bn * Wn * Hn * 4;
    float* harr = (float*)p;      p += (size_t)4 * Bn * Wn * 31 * 4;
    float* h1g = (float*)p;       p += (size_t)Bn * Wn * 32 * 4;
    float* h2g = (float*)p;       p += (size_t)Bn * Wn * 32 * 4;
    float* sc = (float*)p;        p += (size_t)Bn * Wn * Cn * 4;

    float* out = (float*)d_out;

    k_zero<<<(Bn * Wn + 255) / 256, 256, 0, stream>>>(cnt, out);
    k_lists<<<(Bn * Sn + 255) / 256, 256, 0, stream>>>(b2t, cnt, lists);
    k_tokproj<<<Bn * 12, 320, 0, stream>>>(hiddens, Wih_f, Wih_b, tokg);
    k_wordmean<<<Bn * Wn, 128, 0, stream>>>(tokg, cnt, lists, bih_f, bih_b, xg);
    k_lstm<<<64, 64, 0, stream>>>(xg, Whh_f, bhh_f, Whh_b, bhh_b, hs);
    k_mlp<<<Bn * Wn, 128, 0, stream>>>(hs, un_W1, un_b1, un_W2, un_b2,
                                       dr_W1, dr_b1, dr_W2, dr_b2, harr, h1g);
    k_gather<<<Bn * Wn * 8 / 256, 256, 0, stream>>>(harr, heads, h2g);
    k_drscore<<<13 * 64, 256, 0, stream>>>(h1g, h2g, dr_U, dr_bias, sc);
    k_loss<<<Bn * (Wn - 1) + Bn * Wn, 64, 0, stream>>>(harr, un_U, un_bias, sc,
                                                       heads, masks, dep_rels, out);
}

// Round 7
// 156.261 us; speedup vs baseline: 1.3389x; 1.3389x over previous
//
#include <hip/hip_runtime.h>

#define Bn 32
#define Wn 128
#define Sn 192
#define Dn 768
#define Hn 10
#define BHn 30
#define Cn 50
#define CAP 8
#define NEGV -1e30f
#define XPAD 4

__device__ __forceinline__ float fsig(float x) {
    return __builtin_amdgcn_rcpf(1.0f + __expf(-x));
}
__device__ __forceinline__ float ftanh(float x) {
    return 1.0f - 2.0f * __builtin_amdgcn_rcpf(1.0f + __expf(2.0f * x));
}
__device__ __forceinline__ float lane_bcast(float v, int srclane) {
    union { float f; int i; } u, w;
    u.f = v;
    w.i = __builtin_amdgcn_readlane(u.i, srclane);
    return w.f;
}
template <int Q>
__device__ __forceinline__ float quad_bcast(float v) {
    union { float f; int i; } u, w;
    u.f = v;
    w.i = __builtin_amdgcn_mov_dpp(u.i, (Q << 6) | (Q << 4) | (Q << 2) | Q, 0xf, 0xf, true);
    return w.f;
}

// ---------------- zero counters + output ----------------
__global__ void k_zero(int* cnt, float* out) {
    int i = blockIdx.x * blockDim.x + threadIdx.x;
    if (i < Bn * Wn) cnt[i] = 0;
    if (i == 0) out[0] = 0.f;
}

// ---------------- build token->word inverse lists ----------------
__global__ void k_lists(const int* __restrict__ b2t, int* cnt, int* lists) {
    int idx = blockIdx.x * blockDim.x + threadIdx.x;
    if (idx >= Bn * Sn) return;
    int b = idx / Sn;
    int w = b2t[idx];
    if (w < 0 || w >= Wn) return;
    int s = idx % Sn;
    int pos = atomicAdd(&cnt[b * Wn + w], 1);
    if (pos < CAP) lists[(b * Wn + w) * CAP + pos] = s;
}

// ---------------- token projection: 4 w-rows x 1 token per thread ----------------
// tokg[b,s,dir,off] = (sum_l hid[l,b,s+1,:]) . Wih[row,:]   (bias + /(3*cnt) later)
__global__ __launch_bounds__(320) void k_tokproj(const float* __restrict__ hid,
                                                 const float* __restrict__ Wf,
                                                 const float* __restrict__ Wb,
                                                 float* __restrict__ tokg) {
    __shared__ float xl[16 * (Dn + XPAD)];
    int b = blockIdx.x / 12;
    int sc0 = blockIdx.x % 12;
    int s0 = sc0 * 16;
    for (int idx = threadIdx.x; idx < 16 * (Dn / 4); idx += 320) {
        int r = idx / (Dn / 4), k4 = idx % (Dn / 4);
        size_t rowbase = ((size_t)b * (Sn + 1) + (s0 + r + 1)) * Dn;
        float4 v0 = ((const float4*)(hid + rowbase))[k4];
        float4 v1 = ((const float4*)(hid + (size_t)Bn * (Sn + 1) * Dn + rowbase))[k4];
        float4 v2 = ((const float4*)(hid + (size_t)2 * Bn * (Sn + 1) * Dn + rowbase))[k4];
        float4 v;
        v.x = v0.x + v1.x + v2.x; v.y = v0.y + v1.y + v2.y;
        v.z = v0.z + v1.z + v2.z; v.w = v0.w + v1.w + v2.w;
        ((float4*)(xl + r * (Dn + XPAD)))[k4] = v;
    }
    __syncthreads();

    int rq = threadIdx.x >> 4;  // 0..19 -> rows rq*4..rq*4+3
    int tk = threadIdx.x & 15;  // token 0..15
    const float4* xp = (const float4*)(xl + tk * (Dn + XPAD));
    const float4* wr[4];
#pragma unroll
    for (int rr = 0; rr < 4; ++rr) {
        int row = rq * 4 + rr;          // 0..79
        int dir = row / 40, r40 = row % 40;
        wr[rr] = (const float4*)((dir ? Wb : Wf) + r40 * Dn);
    }
    float a0 = 0.f, a1 = 0.f, a2 = 0.f, a3 = 0.f;
    for (int k = 0; k < Dn / 4; ++k) {
        float4 xv = xp[k];
        float4 w0 = wr[0][k], w1 = wr[1][k], w2 = wr[2][k], w3 = wr[3][k];
        a0 += w0.x * xv.x + w0.y * xv.y + w0.z * xv.z + w0.w * xv.w;
        a1 += w1.x * xv.x + w1.y * xv.y + w1.z * xv.z + w1.w * xv.w;
        a2 += w2.x * xv.x + w2.y * xv.y + w2.z * xv.z + w2.w * xv.w;
        a3 += w3.x * xv.x + w3.y * xv.y + w3.z * xv.z + w3.w * xv.w;
    }
    float av[4] = {a0, a1, a2, a3};
#pragma unroll
    for (int rr = 0; rr < 4; ++rr) {
        int row = rq * 4 + rr;
        int dir = row / 40, r40 = row % 40;
        int off = (r40 % 10) * 4 + (r40 / 10); // j*4+gate
        tokg[(((size_t)b * Sn + s0 + tk) * 2 + dir) * 40 + off] = av[rr];
    }
}

// ---------------- segment-mean in gate space + bias -> xg ----------------
__global__ __launch_bounds__(128) void k_wordmean(const float* __restrict__ tokg,
                                                  const int* __restrict__ cnt,
                                                  const int* __restrict__ lists,
                                                  const float* __restrict__ bih_f,
                                                  const float* __restrict__ bih_b,
                                                  float* __restrict__ xg) {
    int bw = blockIdx.x; // b*Wn + w
    int b = bw / Wn, w = bw % Wn;
    int l = threadIdx.x;
    if (l >= 80) return;
    int dir = l / 40, off = l % 40;
    int c = cnt[bw];
    int cc = c < CAP ? c : CAP;
    float acc = 0.f;
    for (int tk = 0; tk < cc; ++tk) {
        int s = lists[bw * CAP + tk];
        acc += tokg[(((size_t)b * Sn + s) * 2 + dir) * 40 + off];
    }
    float inv = 1.0f / (3.0f * (float)(c > 0 ? c : 1));
    int brow = (off & 3) * 10 + (off >> 2); // gate*10 + j
    float bias = (dir ? bih_b : bih_f)[brow];
    xg[((size_t)(dir * Bn + b) * Wn + w) * 40 + off] = acc * inv + bias;
}

// ---------------- LSTM scan: 1 seq/wave, readlane h-broadcast, DPP gate combine ----------------
__global__ __launch_bounds__(64) void k_lstm(const float* __restrict__ xg,
                                             const float* __restrict__ Whh_f, const float* __restrict__ bhh_f,
                                             const float* __restrict__ Whh_b, const float* __restrict__ bhh_b,
                                             float* __restrict__ hs) {
    int lane = threadIdx.x;
    int seq = blockIdx.x;      // 0..63
    int dir = seq >> 5;
    int l = lane < 40 ? lane : 39;
    int j = l >> 2, G = l & 3;

    const float* Whh = dir ? Whh_b : Whh_f;
    const float* bhh = dir ? bhh_b : bhh_f;
    float wk[Hn];
#pragma unroll
    for (int k = 0; k < Hn; ++k) wk[k] = Whh[(G * Hn + j) * Hn + k];
    float bias = bhh[G * Hn + j];

    const float* xbase = xg + (size_t)seq * Wn * 40; // layout [t][j*4+gate]
    float* hbase = hs + (size_t)seq * Wn * Hn;
    bool st = (G == 0) && (lane < 40);

    float h = 0.f, c = 0.f;
    int dt = dir ? -1 : 1;
    int t = dir ? (Wn - 1) : 0;
    float xq[4];
    xq[0] = xbase[t * 40 + l];
    xq[1] = xbase[(t + dt) * 40 + l];
    xq[2] = xbase[(t + 2 * dt) * 40 + l];

#pragma unroll 4
    for (int step = 0; step < Wn; ++step) {
        float xv = xq[step & 3];
        xq[(step + 3) & 3] = xbase[(t + 3 * dt) * 40 + l]; // prefetch 3 ahead
        float hb[Hn];
#pragma unroll
        for (int k = 0; k < Hn; ++k) hb[k] = lane_bcast(h, 4 * k);
        float ga = xv, gb = bias;
#pragma unroll
        for (int k = 0; k < 5; ++k) ga += wk[k] * hb[k];
#pragma unroll
        for (int k = 5; k < Hn; ++k) gb += wk[k] * hb[k];
        float g = ga + gb;
        float gin = (G == 2) ? 2.f * g : g;
        float s = fsig(gin);
        float av = (G == 2) ? 2.f * s - 1.f : s;
        float ai = quad_bcast<0>(av);
        float af = quad_bcast<1>(av);
        float ag = quad_bcast<2>(av);
        float ao = quad_bcast<3>(av);
        c = af * c + ai * ag;
        h = ao * ftanh(c);
        if (st) hbase[t * Hn + j] = h;
        t += dt;
    }
}

// ---------------- MLP heads -> padded hpad[which][n][32] ----------------
__global__ __launch_bounds__(128) void k_mlp(const float* __restrict__ hs,
                                             const float* __restrict__ uW1, const float* __restrict__ ub1,
                                             const float* __restrict__ uW2, const float* __restrict__ ub2,
                                             const float* __restrict__ dW1, const float* __restrict__ db1,
                                             const float* __restrict__ dW2, const float* __restrict__ db2,
                                             float* __restrict__ hpad) {
    int bt = blockIdx.x; // b*Wn + t
    int b = bt / Wn, t = bt % Wn;
    __shared__ float x[20];
    int tid = threadIdx.x;
    if (tid < 20) {
        x[tid] = (tid < Hn) ? hs[((size_t)(0 * Bn + b) * Wn + t) * Hn + tid]
                            : hs[((size_t)(1 * Bn + b) * Wn + t) * Hn + (tid - Hn)];
    }
    __syncthreads();
    if (tid >= 124) { // pads for all 4 heads
        hpad[((size_t)(tid - 124) * Bn * Wn + bt) * 32 + 31] = 0.f;
        return;
    }
    int which = tid / 31, k = tid % 31;
    float v;
    if (k == 30) {
        v = 1.0f;
    } else {
        const float* Wm;
        const float* bv;
        if (which == 0) { Wm = uW1; bv = ub1; }
        else if (which == 1) { Wm = uW2; bv = ub2; }
        else if (which == 2) { Wm = dW1; bv = db1; }
        else { Wm = dW2; bv = db2; }
        float a = bv[k];
#pragma unroll
        for (int d = 0; d < 20; ++d) a += x[d] * Wm[d * BHn + k];
        v = a > 0.f ? a : 0.f;
    }
    hpad[((size_t)which * Bn * Wn + bt) * 32 + k] = v;
}

// ---------------- gather dr-h2 rows at j=head ----------------
__global__ __launch_bounds__(256) void k_gather(const float* __restrict__ hpad,
                                                const int* __restrict__ heads,
                                                float* __restrict__ h2g) {
    int idx = blockIdx.x * 256 + threadIdx.x; // n*8 + q
    int n = idx >> 3, q = idx & 7;
    int b = n >> 7;
    int jh = heads[n];
    if (jh < 0 || jh >= Wn) jh = 0;
    const float4* src = (const float4*)(hpad + ((size_t)3 * Bn * Wn + b * Wn + jh) * 32);
    ((float4*)(h2g + (size_t)n * 32))[q] = src[q];
}

// ---------------- deprel scores: thread=(n,o), U broadcast from LDS, h1/h2 in regs ----------------
__global__ __launch_bounds__(256) void k_drscore(const float* __restrict__ h1g,
                                                 const float* __restrict__ h2g,
                                                 const float* __restrict__ U, const float* __restrict__ dbias,
                                                 float* __restrict__ sc) {
    int nc = blockIdx.x & 63;
    int oq = blockIdx.x >> 6; // 0..12
    __shared__ float Ul[4][992]; // row stride 32 per h (aligned b128)
    int tid = threadIdx.x;
    for (int idx = tid; idx < 4 * 992; idx += 256) {
        int o = idx / 992, r = idx - o * 992;
        int h = r >> 5, g = r & 31;
        int oo = oq * 4 + o; if (oo >= Cn) oo = Cn - 1;
        Ul[o][r] = (g < 31) ? U[(size_t)oo * 961 + h * 31 + g] : 0.f;
    }
    int w = tid >> 6, lane = tid & 63;
    int o = oq * 4 + w;
    int n = nc * 64 + lane;
    float h2r[32];
    {
        const float4* p = (const float4*)(h2g + (size_t)n * 32);
#pragma unroll
        for (int q = 0; q < 8; ++q) {
            float4 v = p[q];
            h2r[4 * q + 0] = v.x; h2r[4 * q + 1] = v.y;
            h2r[4 * q + 2] = v.z; h2r[4 * q + 3] = v.w;
        }
    }
    float h1r[32];
    {
        const float4* p = (const float4*)(h1g + (size_t)n * 32);
#pragma unroll
        for (int q = 0; q < 8; ++q) {
            float4 v = p[q];
            h1r[4 * q + 0] = v.x; h1r[4 * q + 1] = v.y;
            h1r[4 * q + 2] = v.z; h1r[4 * q + 3] = v.w;
        }
    }
    __syncthreads();
    const float* up = Ul[w];
    float acc = 0.f;
    for (int h = 0; h < 31; ++h) {
        float t = 0.f;
#pragma unroll
        for (int g = 0; g < 32; ++g) t += up[h * 32 + g] * h2r[g];
        acc += h1r[h] * t;
    }
    if (o < Cn) sc[(size_t)n * Cn + o] = acc + dbias[o];
}

// ---------------- fused losses: one block per batch b ----------------
// unlab: tg = h1.U0 once; scores 4i x 16j per thread; online softmax; 8-lane combine.
// deprel CE folded in (thread = n). One atomic per block (32 total).
__global__ __launch_bounds__(256) void k_loss2(const float* __restrict__ hpad,
                                               const float* __restrict__ U0, const float* __restrict__ ubias,
                                               const float* __restrict__ sc,
                                               const int* __restrict__ heads,
                                               const unsigned char* __restrict__ masks,
                                               const int* __restrict__ dep_rels,
                                               float* __restrict__ out) {
    int b = blockIdx.x;
    int tid = threadIdx.x;
    __shared__ float h2s[128 * 36];
    __shared__ float tg[128 * 36];
    __shared__ float U0l[992];
    __shared__ float red[256];
    const float* h1a = hpad + (size_t)b * Wn * 32;                 // un h1 (padded)
    const float* h2a = hpad + ((size_t)Bn * Wn + b * Wn) * 32;     // un h2 (padded)
    for (int idx = tid; idx < 128 * 32; idx += 256)
        h2s[(idx >> 5) * 36 + (idx & 31)] = h2a[idx];
    for (int idx = tid; idx < 992; idx += 256) {
        int g = idx & 31;
        U0l[idx] = (g < 31) ? U0[(idx >> 5) * 31 + g] : 0.f;
    }
    __syncthreads();
    // tg[i][l] = sum_h h1[i][h] * U0[h][l]; lane owns column l, 16 rows each
    {
        int l = tid & 31, ig = tid >> 5; // ig 0..7
        float ur[31];
#pragma unroll
        for (int h = 0; h < 31; ++h) ur[h] = U0l[h * 32 + l];
        for (int ii = 0; ii < 16; ++ii) {
            int i = ig * 16 + ii;
            const float4* hp = (const float4*)(h1a + (size_t)i * 32);
            float hr[32];
#pragma unroll
            for (int q = 0; q < 8; ++q) {
                float4 v = hp[q];
                hr[4 * q] = v.x; hr[4 * q + 1] = v.y; hr[4 * q + 2] = v.z; hr[4 * q + 3] = v.w;
            }
            float a = 0.f;
#pragma unroll
            for (int h = 0; h < 31; ++h) a += hr[h] * ur[h];
            tg[i * 36 + l] = a;
        }
    }
    __syncthreads();
    float acc = 0.f;
    {
        int jg = tid & 7, ig2 = tid >> 3; // ig2 0..31 -> 4 i's; jg -> 16 j's
        float ub = ubias[0];
        float4 tq[4][8];
#pragma unroll
        for (int ii = 0; ii < 4; ++ii) {
            const float4* tp = (const float4*)(tg + (ig2 * 4 + ii) * 36);
#pragma unroll
            for (int q = 0; q < 8; ++q) tq[ii][q] = tp[q];
        }
        float m[4], lsum[4], sh[4];
        int hd[4];
#pragma unroll
        for (int ii = 0; ii < 4; ++ii) {
            m[ii] = -3e38f; lsum[ii] = 0.f; sh[ii] = 0.f;
            hd[ii] = heads[b * Wn + ig2 * 4 + ii];
        }
        for (int jj = 0; jj < 16; ++jj) {
            int j = jg * 16 + jj;
            const float4* h2p = (const float4*)(h2s + j * 36);
            float4 hq[8];
#pragma unroll
            for (int q = 0; q < 8; ++q) hq[q] = h2p[q];
#pragma unroll
            for (int ii = 0; ii < 4; ++ii) {
                int i = ig2 * 4 + ii;
                float s = ub;
#pragma unroll
                for (int q = 0; q < 8; ++q) {
                    s += tq[ii][q].x * hq[q].x + tq[ii][q].y * hq[q].y
                       + tq[ii][q].z * hq[q].z + tq[ii][q].w * hq[q].w;
                }
                if (j == i) s = NEGV;
                float mn = fmaxf(m[ii], s);
                lsum[ii] = lsum[ii] * __expf(m[ii] - mn) + __expf(s - mn);
                m[ii] = mn;
                if (j == hd[ii]) sh[ii] = s;
            }
        }
#pragma unroll
        for (int ii = 0; ii < 4; ++ii) {
            float shv = (jg == (hd[ii] >> 4)) ? sh[ii] : 0.f;
            float mm = m[ii], ll = lsum[ii];
#pragma unroll
            for (int off = 1; off < 8; off <<= 1) {
                float m2 = __shfl_xor(mm, off);
                float l2 = __shfl_xor(ll, off);
                float mn = fmaxf(mm, m2);
                ll = ll * __expf(mm - mn) + l2 * __expf(m2 - mn);
                mm = mn;
                shv += __shfl_xor(shv, off);
            }
            if (jg == 0) {
                int i = ig2 * 4 + ii;
                if (i >= 1 && !masks[b * Wn + i])
                    acc += -(shv - (mm + __logf(ll)));
            }
        }
    }
    // deprel CE for this batch's 128 rows
    if (tid < 128) {
        int n = b * Wn + tid;
        int r = dep_rels[n];
        if (r != 0 && r < Cn) {
            const float* sp = sc + (size_t)n * Cn;
            float mm = sp[0];
            for (int o = 1; o < Cn; ++o) mm = fmaxf(mm, sp[o]);
            float e = 0.f;
            for (int o = 0; o < Cn; ++o) e += __expf(sp[o] - mm);
            acc += -(sp[r] - (mm + __logf(e)));
        }
    }
    red[tid] = acc;
    __syncthreads();
    for (int off = 128; off > 0; off >>= 1) {
        if (tid < off) red[tid] += red[tid + off];
        __syncthreads();
    }
    if (tid == 0) atomicAdd(out, red[0]);
}

extern "C" void kernel_launch(void* const* d_in, const int* in_sizes, int n_in,
                              void* d_out, int out_size, void* d_ws, size_t ws_size,
                              hipStream_t stream) {
    const float* hiddens = (const float*)d_in[0];
    const int* b2t = (const int*)d_in[1];
    const int* heads = (const int*)d_in[2];
    const int* dep_rels = (const int*)d_in[3];
    const unsigned char* masks = (const unsigned char*)d_in[4];
    const float* Wih_f = (const float*)d_in[6];
    const float* Whh_f = (const float*)d_in[7];
    const float* bih_f = (const float*)d_in[8];
    const float* bhh_f = (const float*)d_in[9];
    const float* Wih_b = (const float*)d_in[10];
    const float* Whh_b = (const float*)d_in[11];
    const float* bih_b = (const float*)d_in[12];
    const float* bhh_b = (const float*)d_in[13];
    const float* un_W1 = (const float*)d_in[14];
    const float* un_b1 = (const float*)d_in[15];
    const float* un_W2 = (const float*)d_in[16];
    const float* un_b2 = (const float*)d_in[17];
    const float* un_U  = (const float*)d_in[18];
    const float* un_bias = (const float*)d_in[19];
    const float* dr_W1 = (const float*)d_in[20];
    const float* dr_b1 = (const float*)d_in[21];
    const float* dr_W2 = (const float*)d_in[22];
    const float* dr_b2 = (const float*)d_in[23];
    const float* dr_U  = (const float*)d_in[24];
    const float* dr_bias = (const float*)d_in[25];

    char* p = (char*)d_ws;
    int* cnt = (int*)p;           p += (size_t)Bn * Wn * 4;
    int* lists = (int*)p;         p += (size_t)Bn * Wn * CAP * 4;
    float* tokg = (float*)p;      p += (size_t)Bn * Sn * 80 * 4;
    float* xg = (float*)p;        p += (size_t)2 * Bn * Wn * 40 * 4;
    float* hs = (float*)p;        p += (size_t)2 * Bn * Wn * Hn * 4;
    float* hpad = (float*)p;      p += (size_t)4 * Bn * Wn * 32 * 4;
    float* h2g = (float*)p;       p += (size_t)Bn * Wn * 32 * 4;
    float* sc = (float*)p;        p += (size_t)Bn * Wn * Cn * 4;

    float* out = (float*)d_out;

    k_zero<<<(Bn * Wn + 255) / 256, 256, 0, stream>>>(cnt, out);
    k_lists<<<(Bn * Sn + 255) / 256, 256, 0, stream>>>(b2t, cnt, lists);
    k_tokproj<<<Bn * 12, 320, 0, stream>>>(hiddens, Wih_f, Wih_b, tokg);
    k_wordmean<<<Bn * Wn, 128, 0, stream>>>(tokg, cnt, lists, bih_f, bih_b, xg);
    k_lstm<<<64, 64, 0, stream>>>(xg, Whh_f, bhh_f, Whh_b, bhh_b, hs);
    k_mlp<<<Bn * Wn, 128, 0, stream>>>(hs, un_W1, un_b1, un_W2, un_b2,
                                       dr_W1, dr_b1, dr_W2, dr_b2, hpad);
    k_gather<<<Bn * Wn * 8 / 256, 256, 0, stream>>>(hpad, heads, h2g);
    k_drscore<<<13 * 64, 256, 0, stream>>>(hpad + (size_t)2 * Bn * Wn * 32, h2g, dr_U, dr_bias, sc);
    k_loss2<<<Bn, 256, 0, stream>>>(hpad, un_U, un_bias, sc, heads, masks, dep_rels, out);
}

// Round 8
// 148.317 us; speedup vs baseline: 1.4106x; 1.0536x over previous
//
#include <hip/hip_runtime.h>

#define Bn 32
#define Wn 128
#define Sn 192
#define Dn 768
#define Hn 10
#define BHn 30
#define Cn 50
#define CAP 8
#define NEGV -1e30f
#define XPAD 4

__device__ __forceinline__ float fsig(float x) {
    return __builtin_amdgcn_rcpf(1.0f + __expf(-x));
}
__device__ __forceinline__ float ftanh(float x) {
    return 1.0f - 2.0f * __builtin_amdgcn_rcpf(1.0f + __expf(2.0f * x));
}
__device__ __forceinline__ float lane_bcast(float v, int srclane) {
    union { float f; int i; } u, w;
    u.f = v;
    w.i = __builtin_amdgcn_readlane(u.i, srclane);
    return w.f;
}
template <int Q>
__device__ __forceinline__ float quad_bcast(float v) {
    union { float f; int i; } u, w;
    u.f = v;
    w.i = __builtin_amdgcn_mov_dpp(u.i, (Q << 6) | (Q << 4) | (Q << 2) | Q, 0xf, 0xf, true);
    return w.f;
}

// ---------------- zero counters + output ----------------
__global__ void k_zero(int* cnt, float* out) {
    int i = blockIdx.x * blockDim.x + threadIdx.x;
    if (i < Bn * Wn) cnt[i] = 0;
    if (i == 0) out[0] = 0.f;
}

// ---------------- build token->word inverse lists ----------------
__global__ void k_lists(const int* __restrict__ b2t, int* cnt, int* lists) {
    int idx = blockIdx.x * blockDim.x + threadIdx.x;
    if (idx >= Bn * Sn) return;
    int b = idx / Sn;
    int w = b2t[idx];
    if (w < 0 || w >= Wn) return;
    int s = idx % Sn;
    int pos = atomicAdd(&cnt[b * Wn + w], 1);
    if (pos < CAP) lists[(b * Wn + w) * CAP + pos] = s;
}

// ---------------- token projection, K-split by 4 for occupancy ----------------
// block = (16 tokens) x (80 rows) x (K-quarter of 192)
// tokg4[kq][n][co] partial; co = dir*40 + j*4 + gate
__global__ __launch_bounds__(320) void k_tokproj(const float* __restrict__ hid,
                                                 const float* __restrict__ Wf,
                                                 const float* __restrict__ Wb,
                                                 float* __restrict__ tokg4) {
    __shared__ float xl[16 * 196]; // 16 tokens x 192 k (+4 pad), summed over 3 layers
    int tb = blockIdx.x >> 2;
    int kq = blockIdx.x & 3;
    int b = tb / 12;
    int s0 = (tb % 12) * 16;
    int k0 = kq * 192;
    for (int idx = threadIdx.x; idx < 16 * 48; idx += 320) {
        int r = idx / 48, k4 = idx % 48;
        size_t rowbase = ((size_t)b * (Sn + 1) + (s0 + r + 1)) * Dn + k0 + 4 * k4;
        float4 v0 = *(const float4*)(hid + rowbase);
        float4 v1 = *(const float4*)(hid + (size_t)Bn * (Sn + 1) * Dn + rowbase);
        float4 v2 = *(const float4*)(hid + (size_t)2 * Bn * (Sn + 1) * Dn + rowbase);
        float4 v;
        v.x = v0.x + v1.x + v2.x; v.y = v0.y + v1.y + v2.y;
        v.z = v0.z + v1.z + v2.z; v.w = v0.w + v1.w + v2.w;
        *(float4*)(xl + r * 196 + 4 * k4) = v;
    }
    __syncthreads();

    int rq = threadIdx.x >> 4;  // 0..19 -> rows rq*4..rq*4+3
    int tk = threadIdx.x & 15;  // token 0..15
    const float4* xp = (const float4*)(xl + tk * 196);
    const float4* wr[4];
#pragma unroll
    for (int rr = 0; rr < 4; ++rr) {
        int row = rq * 4 + rr;          // 0..79
        int dir = row / 40, r40 = row % 40;
        wr[rr] = (const float4*)((dir ? Wb : Wf) + r40 * Dn + k0);
    }
    float a0 = 0.f, a1 = 0.f, a2 = 0.f, a3 = 0.f;
#pragma unroll 2
    for (int k = 0; k < 48; ++k) {
        float4 xv = xp[k];
        float4 w0 = wr[0][k], w1 = wr[1][k], w2 = wr[2][k], w3 = wr[3][k];
        a0 += w0.x * xv.x + w0.y * xv.y + w0.z * xv.z + w0.w * xv.w;
        a1 += w1.x * xv.x + w1.y * xv.y + w1.z * xv.z + w1.w * xv.w;
        a2 += w2.x * xv.x + w2.y * xv.y + w2.z * xv.z + w2.w * xv.w;
        a3 += w3.x * xv.x + w3.y * xv.y + w3.z * xv.z + w3.w * xv.w;
    }
    float av[4] = {a0, a1, a2, a3};
    size_t nbase = ((size_t)kq * (Bn * Sn) + (size_t)b * Sn + s0 + tk) * 80;
#pragma unroll
    for (int rr = 0; rr < 4; ++rr) {
        int row = rq * 4 + rr;
        int dir = row / 40, r40 = row % 40;
        int co = dir * 40 + (r40 % 10) * 4 + (r40 / 10);
        tokg4[nbase + co] = av[rr];
    }
}

// ---------------- segment-mean in gate space (+ sum of 4 K-partials) + bias -> xg ----------------
__global__ __launch_bounds__(128) void k_wordmean(const float* __restrict__ tokg4,
                                                  const int* __restrict__ cnt,
                                                  const int* __restrict__ lists,
                                                  const float* __restrict__ bih_f,
                                                  const float* __restrict__ bih_b,
                                                  float* __restrict__ xg) {
    const size_t NT80 = (size_t)Bn * Sn * 80;
    int bw = blockIdx.x; // b*Wn + w
    int b = bw / Wn, w = bw % Wn;
    int l = threadIdx.x;
    if (l >= 80) return;
    int dir = l / 40, off = l % 40;
    int c = cnt[bw];
    int cc = c < CAP ? c : CAP;
    float acc = 0.f;
    for (int tk = 0; tk < cc; ++tk) {
        int s = lists[bw * CAP + tk];
        size_t base = ((size_t)b * Sn + s) * 80 + l;
        acc += tokg4[base] + tokg4[base + NT80]
             + tokg4[base + 2 * NT80] + tokg4[base + 3 * NT80];
    }
    float inv = 1.0f / (3.0f * (float)(c > 0 ? c : 1));
    int brow = (off & 3) * 10 + (off >> 2); // gate*10 + j
    float bias = (dir ? bih_b : bih_f)[brow];
    xg[((size_t)(dir * Bn + b) * Wn + w) * 40 + off] = acc * inv + bias;
}

// ---------------- LSTM scan: 1 seq/wave, readlane h-broadcast, DPP gate combine ----------------
__global__ __launch_bounds__(64) void k_lstm(const float* __restrict__ xg,
                                             const float* __restrict__ Whh_f, const float* __restrict__ bhh_f,
                                             const float* __restrict__ Whh_b, const float* __restrict__ bhh_b,
                                             float* __restrict__ hs) {
    int lane = threadIdx.x;
    int seq = blockIdx.x;      // 0..63
    int dir = seq >> 5;
    int l = lane < 40 ? lane : 39;
    int j = l >> 2, G = l & 3;

    const float* Whh = dir ? Whh_b : Whh_f;
    const float* bhh = dir ? bhh_b : bhh_f;
    float wk[Hn];
#pragma unroll
    for (int k = 0; k < Hn; ++k) wk[k] = Whh[(G * Hn + j) * Hn + k];
    float bias = bhh[G * Hn + j];

    const float* xbase = xg + (size_t)seq * Wn * 40; // layout [t][j*4+gate]
    float* hbase = hs + (size_t)seq * Wn * Hn;
    bool st = (G == 0) && (lane < 40);

    float h = 0.f, c = 0.f;
    int dt = dir ? -1 : 1;
    int t = dir ? (Wn - 1) : 0;
    float xq[4];
    xq[0] = xbase[t * 40 + l];
    xq[1] = xbase[(t + dt) * 40 + l];
    xq[2] = xbase[(t + 2 * dt) * 40 + l];

#pragma unroll 4
    for (int step = 0; step < Wn; ++step) {
        float xv = xq[step & 3];
        xq[(step + 3) & 3] = xbase[(t + 3 * dt) * 40 + l]; // prefetch 3 ahead
        float hb[Hn];
#pragma unroll
        for (int k = 0; k < Hn; ++k) hb[k] = lane_bcast(h, 4 * k);
        float ga = xv, gb = bias;
#pragma unroll
        for (int k = 0; k < 5; ++k) ga += wk[k] * hb[k];
#pragma unroll
        for (int k = 5; k < Hn; ++k) gb += wk[k] * hb[k];
        float g = ga + gb;
        float gin = (G == 2) ? 2.f * g : g;
        float s = fsig(gin);
        float av = (G == 2) ? 2.f * s - 1.f : s;
        float ai = quad_bcast<0>(av);
        float af = quad_bcast<1>(av);
        float ag = quad_bcast<2>(av);
        float ao = quad_bcast<3>(av);
        c = af * c + ai * ag;
        h = ao * ftanh(c);
        if (st) hbase[t * Hn + j] = h;
        t += dt;
    }
}

// ---------------- MLP heads -> padded hpad[which][n][32] ----------------
__global__ __launch_bounds__(128) void k_mlp(const float* __restrict__ hs,
                                             const float* __restrict__ uW1, const float* __restrict__ ub1,
                                             const float* __restrict__ uW2, const float* __restrict__ ub2,
                                             const float* __restrict__ dW1, const float* __restrict__ db1,
                                             const float* __restrict__ dW2, const float* __restrict__ db2,
                                             float* __restrict__ hpad) {
    int bt = blockIdx.x; // b*Wn + t
    int b = bt / Wn, t = bt % Wn;
    __shared__ float x[20];
    int tid = threadIdx.x;
    if (tid < 20) {
        x[tid] = (tid < Hn) ? hs[((size_t)(0 * Bn + b) * Wn + t) * Hn + tid]
                            : hs[((size_t)(1 * Bn + b) * Wn + t) * Hn + (tid - Hn)];
    }
    __syncthreads();
    if (tid >= 124) { // pads for all 4 heads
        hpad[((size_t)(tid - 124) * Bn * Wn + bt) * 32 + 31] = 0.f;
        return;
    }
    int which = tid / 31, k = tid % 31;
    float v;
    if (k == 30) {
        v = 1.0f;
    } else {
        const float* Wm;
        const float* bv;
        if (which == 0) { Wm = uW1; bv = ub1; }
        else if (which == 1) { Wm = uW2; bv = ub2; }
        else if (which == 2) { Wm = dW1; bv = db1; }
        else { Wm = dW2; bv = db2; }
        float a = bv[k];
#pragma unroll
        for (int d = 0; d < 20; ++d) a += x[d] * Wm[d * BHn + k];
        v = a > 0.f ? a : 0.f;
    }
    hpad[((size_t)which * Bn * Wn + bt) * 32 + k] = v;
}

// ---------------- gather dr-h2 rows at j=head ----------------
__global__ __launch_bounds__(256) void k_gather(const float* __restrict__ hpad,
                                                const int* __restrict__ heads,
                                                float* __restrict__ h2g) {
    int idx = blockIdx.x * 256 + threadIdx.x; // n*8 + q
    int n = idx >> 3, q = idx & 7;
    int b = n >> 7;
    int jh = heads[n];
    if (jh < 0 || jh >= Wn) jh = 0;
    const float4* src = (const float4*)(hpad + ((size_t)3 * Bn * Wn + b * Wn + jh) * 32);
    ((float4*)(h2g + (size_t)n * 32))[q] = src[q];
}

// ---------------- deprel scores: thread=(n,o), U broadcast from LDS, h1/h2 in regs ----------------
__global__ __launch_bounds__(256) void k_drscore(const float* __restrict__ h1g,
                                                 const float* __restrict__ h2g,
                                                 const float* __restrict__ U, const float* __restrict__ dbias,
                                                 float* __restrict__ sc) {
    int nc = blockIdx.x & 63;
    int oq = blockIdx.x >> 6; // 0..12
    __shared__ float Ul[4][992]; // row stride 32 per h (aligned b128)
    int tid = threadIdx.x;
    for (int idx = tid; idx < 4 * 992; idx += 256) {
        int o = idx / 992, r = idx - o * 992;
        int h = r >> 5, g = r & 31;
        int oo = oq * 4 + o; if (oo >= Cn) oo = Cn - 1;
        Ul[o][r] = (g < 31) ? U[(size_t)oo * 961 + h * 31 + g] : 0.f;
    }
    int w = tid >> 6, lane = tid & 63;
    int o = oq * 4 + w;
    int n = nc * 64 + lane;
    float h2r[32];
    {
        const float4* p = (const float4*)(h2g + (size_t)n * 32);
#pragma unroll
        for (int q = 0; q < 8; ++q) {
            float4 v = p[q];
            h2r[4 * q + 0] = v.x; h2r[4 * q + 1] = v.y;
            h2r[4 * q + 2] = v.z; h2r[4 * q + 3] = v.w;
        }
    }
    float h1r[32];
    {
        const float4* p = (const float4*)(h1g + (size_t)n * 32);
#pragma unroll
        for (int q = 0; q < 8; ++q) {
            float4 v = p[q];
            h1r[4 * q + 0] = v.x; h1r[4 * q + 1] = v.y;
            h1r[4 * q + 2] = v.z; h1r[4 * q + 3] = v.w;
        }
    }
    __syncthreads();
    const float* up = Ul[w];
    float acc = 0.f;
    for (int h = 0; h < 31; ++h) {
        float t = 0.f;
#pragma unroll
        for (int g = 0; g < 32; ++g) t += up[h * 32 + g] * h2r[g];
        acc += h1r[h] * t;
    }
    if (o < Cn) sc[(size_t)n * Cn + o] = acc + dbias[o];
}

// ---------------- fused losses: one block per batch b ----------------
__global__ __launch_bounds__(256) void k_loss2(const float* __restrict__ hpad,
                                               const float* __restrict__ U0, const float* __restrict__ ubias,
                                               const float* __restrict__ sc,
                                               const int* __restrict__ heads,
                                               const unsigned char* __restrict__ masks,
                                               const int* __restrict__ dep_rels,
                                               float* __restrict__ out) {
    int b = blockIdx.x;
    int tid = threadIdx.x;
    __shared__ float h2s[128 * 36];
    __shared__ float tg[128 * 36];
    __shared__ float U0l[992];
    __shared__ float red[256];
    const float* h1a = hpad + (size_t)b * Wn * 32;                 // un h1 (padded)
    const float* h2a = hpad + ((size_t)Bn * Wn + b * Wn) * 32;     // un h2 (padded)
    for (int idx = tid; idx < 128 * 32; idx += 256)
        h2s[(idx >> 5) * 36 + (idx & 31)] = h2a[idx];
    for (int idx = tid; idx < 992; idx += 256) {
        int g = idx & 31;
        U0l[idx] = (g < 31) ? U0[(idx >> 5) * 31 + g] : 0.f;
    }
    __syncthreads();
    {
        int l = tid & 31, ig = tid >> 5; // ig 0..7
        float ur[31];
#pragma unroll
        for (int h = 0; h < 31; ++h) ur[h] = U0l[h * 32 + l];
        for (int ii = 0; ii < 16; ++ii) {
            int i = ig * 16 + ii;
            const float4* hp = (const float4*)(h1a + (size_t)i * 32);
            float hr[32];
#pragma unroll
            for (int q = 0; q < 8; ++q) {
                float4 v = hp[q];
                hr[4 * q] = v.x; hr[4 * q + 1] = v.y; hr[4 * q + 2] = v.z; hr[4 * q + 3] = v.w;
            }
            float a = 0.f;
#pragma unroll
            for (int h = 0; h < 31; ++h) a += hr[h] * ur[h];
            tg[i * 36 + l] = a;
        }
    }
    __syncthreads();
    float acc = 0.f;
    {
        int jg = tid & 7, ig2 = tid >> 3; // ig2 0..31 -> 4 i's; jg -> 16 j's
        float ub = ubias[0];
        float4 tq[4][8];
#pragma unroll
        for (int ii = 0; ii < 4; ++ii) {
            const float4* tp = (const float4*)(tg + (ig2 * 4 + ii) * 36);
#pragma unroll
            for (int q = 0; q < 8; ++q) tq[ii][q] = tp[q];
        }
        float m[4], lsum[4], sh[4];
        int hd[4];
#pragma unroll
        for (int ii = 0; ii < 4; ++ii) {
            m[ii] = -3e38f; lsum[ii] = 0.f; sh[ii] = 0.f;
            hd[ii] = heads[b * Wn + ig2 * 4 + ii];
        }
        for (int jj = 0; jj < 16; ++jj) {
            int j = jg * 16 + jj;
            const float4* h2p = (const float4*)(h2s + j * 36);
            float4 hq[8];
#pragma unroll
            for (int q = 0; q < 8; ++q) hq[q] = h2p[q];
#pragma unroll
            for (int ii = 0; ii < 4; ++ii) {
                int i = ig2 * 4 + ii;
                float s = ub;
#pragma unroll
                for (int q = 0; q < 8; ++q) {
                    s += tq[ii][q].x * hq[q].x + tq[ii][q].y * hq[q].y
                       + tq[ii][q].z * hq[q].z + tq[ii][q].w * hq[q].w;
                }
                if (j == i) s = NEGV;
                float mn = fmaxf(m[ii], s);
                lsum[ii] = lsum[ii] * __expf(m[ii] - mn) + __expf(s - mn);
                m[ii] = mn;
                if (j == hd[ii]) sh[ii] = s;
            }
        }
#pragma unroll
        for (int ii = 0; ii < 4; ++ii) {
            float shv = (jg == (hd[ii] >> 4)) ? sh[ii] : 0.f;
            float mm = m[ii], ll = lsum[ii];
#pragma unroll
            for (int off = 1; off < 8; off <<= 1) {
                float m2 = __shfl_xor(mm, off);
                float l2 = __shfl_xor(ll, off);
                float mn = fmaxf(mm, m2);
                ll = ll * __expf(mm - mn) + l2 * __expf(m2 - mn);
                mm = mn;
                shv += __shfl_xor(shv, off);
            }
            if (jg == 0) {
                int i = ig2 * 4 + ii;
                if (i >= 1 && !masks[b * Wn + i])
                    acc += -(shv - (mm + __logf(ll)));
            }
        }
    }
    if (tid < 128) {
        int n = b * Wn + tid;
        int r = dep_rels[n];
        if (r != 0 && r < Cn) {
            const float* sp = sc + (size_t)n * Cn;
            float mm = sp[0];
            for (int o = 1; o < Cn; ++o) mm = fmaxf(mm, sp[o]);
            float e = 0.f;
            for (int o = 0; o < Cn; ++o) e += __expf(sp[o] - mm);
            acc += -(sp[r] - (mm + __logf(e)));
        }
    }
    red[tid] = acc;
    __syncthreads();
    for (int off = 128; off > 0; off >>= 1) {
        if (tid < off) red[tid] += red[tid + off];
        __syncthreads();
    }
    if (tid == 0) atomicAdd(out, red[0]);
}

extern "C" void kernel_launch(void* const* d_in, const int* in_sizes, int n_in,
                              void* d_out, int out_size, void* d_ws, size_t ws_size,
                              hipStream_t stream) {
    const float* hiddens = (const float*)d_in[0];
    const int* b2t = (const int*)d_in[1];
    const int* heads = (const int*)d_in[2];
    const int* dep_rels = (const int*)d_in[3];
    const unsigned char* masks = (const unsigned char*)d_in[4];
    const float* Wih_f = (const float*)d_in[6];
    const float* Whh_f = (const float*)d_in[7];
    const float* bih_f = (const float*)d_in[8];
    const float* bhh_f = (const float*)d_in[9];
    const float* Wih_b = (const float*)d_in[10];
    const float* Whh_b = (const float*)d_in[11];
    const float* bih_b = (const float*)d_in[12];
    const float* bhh_b = (const float*)d_in[13];
    const float* un_W1 = (const float*)d_in[14];
    const float* un_b1 = (const float*)d_in[15];
    const float* un_W2 = (const float*)d_in[16];
    const float* un_b2 = (const float*)d_in[17];
    const float* un_U  = (const float*)d_in[18];
    const float* un_bias = (const float*)d_in[19];
    const float* dr_W1 = (const float*)d_in[20];
    const float* dr_b1 = (const float*)d_in[21];
    const float* dr_W2 = (const float*)d_in[22];
    const float* dr_b2 = (const float*)d_in[23];
    const float* dr_U  = (const float*)d_in[24];
    const float* dr_bias = (const float*)d_in[25];

    char* p = (char*)d_ws;
    int* cnt = (int*)p;           p += (size_t)Bn * Wn * 4;
    int* lists = (int*)p;         p += (size_t)Bn * Wn * CAP * 4;
    float* tokg4 = (float*)p;     p += (size_t)4 * Bn * Sn * 80 * 4;
    float* xg = (float*)p;        p += (size_t)2 * Bn * Wn * 40 * 4;
    float* hs = (float*)p;        p += (size_t)2 * Bn * Wn * Hn * 4;
    float* hpad = (float*)p;      p += (size_t)4 * Bn * Wn * 32 * 4;
    float* h2g = (float*)p;       p += (size_t)Bn * Wn * 32 * 4;
    float* sc = (float*)p;        p += (size_t)Bn * Wn * Cn * 4;

    float* out = (float*)d_out;

    k_zero<<<(Bn * Wn + 255) / 256, 256, 0, stream>>>(cnt, out);
    k_lists<<<(Bn * Sn + 255) / 256, 256, 0, stream>>>(b2t, cnt, lists);
    k_tokproj<<<Bn * 12 * 4, 320, 0, stream>>>(hiddens, Wih_f, Wih_b, tokg4);
    k_wordmean<<<Bn * Wn, 128, 0, stream>>>(tokg4, cnt, lists, bih_f, bih_b, xg);
    k_lstm<<<64, 64, 0, stream>>>(xg, Whh_f, bhh_f, Whh_b, bhh_b, hs);
    k_mlp<<<Bn * Wn, 128, 0, stream>>>(hs, un_W1, un_b1, un_W2, un_b2,
                                       dr_W1, dr_b1, dr_W2, dr_b2, hpad);
    k_gather<<<Bn * Wn * 8 / 256, 256, 0, stream>>>(hpad, heads, h2g);
    k_drscore<<<13 * 64, 256, 0, stream>>>(hpad + (size_t)2 * Bn * Wn * 32, h2g, dr_U, dr_bias, sc);
    k_loss2<<<Bn, 256, 0, stream>>>(hpad, un_U, un_bias, sc, heads, masks, dep_rels, out);
}

// Round 9
// 116.315 us; speedup vs baseline: 1.7987x; 1.2751x over previous
//
#include <hip/hip_runtime.h>

#define Bn 32
#define Wn 128
#define Sn 192
#define Dn 768
#define Hn 10
#define BHn 30
#define Cn 50
#define CAP 8
#define NEGV -1e30f

__device__ __forceinline__ float fsig(float x) {
    return __builtin_amdgcn_rcpf(1.0f + __expf(-x));
}
__device__ __forceinline__ float ftanh(float x) {
    return 1.0f - 2.0f * __builtin_amdgcn_rcpf(1.0f + __expf(2.0f * x));
}
__device__ __forceinline__ float lane_bcast(float v, int srclane) {
    union { float f; int i; } u, w;
    u.f = v;
    w.i = __builtin_amdgcn_readlane(u.i, srclane);
    return w.f;
}
template <int Q>
__device__ __forceinline__ float quad_bcast(float v) {
    union { float f; int i; } u, w;
    u.f = v;
    w.i = __builtin_amdgcn_mov_dpp(u.i, (Q << 6) | (Q << 4) | (Q << 2) | Q, 0xf, 0xf, true);
    return w.f;
}

// ---------------- zero counters + output ----------------
__global__ void k_zero(int* cnt, float* out) {
    int i = blockIdx.x * blockDim.x + threadIdx.x;
    if (i < Bn * Wn) cnt[i] = 0;
    if (i == 0) out[0] = 0.f;
}

// ---------------- build token->word inverse lists ----------------
__global__ void k_lists(const int* __restrict__ b2t, int* cnt, int* lists) {
    int idx = blockIdx.x * blockDim.x + threadIdx.x;
    if (idx >= Bn * Sn) return;
    int b = idx / Sn;
    int w = b2t[idx];
    if (w < 0 || w >= Wn) return;
    int s = idx % Sn;
    int pos = atomicAdd(&cnt[b * Wn + w], 1);
    if (pos < CAP) lists[(b * Wn + w) * CAP + pos] = s;
}

// ---------------- token projection v3: LDS+register-tiled GEMM ----------------
// block = 64 tokens x 80 rows x K-quarter(192); 256 threads;
// thread = 4 tokens x 5 rows (20 accs); x and W both staged in LDS.
// tokg4[kq][n][co] partial, co = dir*40 + j*4 + gate
#define XSTR 196
#define WSTR 68
__global__ __launch_bounds__(256) void k_tokproj(const float* __restrict__ hid,
                                                 const float* __restrict__ Wf,
                                                 const float* __restrict__ Wb,
                                                 float* __restrict__ tokg4) {
    __shared__ float xl[64 * XSTR];  // 64 tokens x 192k (pad to 196)
    __shared__ float wl[80 * WSTR];  // 80 co-rows x 64k (pad to 68)
    int tb = blockIdx.x >> 2;
    int kq = blockIdx.x & 3;
    int b = tb / 3;
    int s0 = (tb % 3) * 64;
    int k0 = kq * 192;
    int tid = threadIdx.x;

    // stage x: sum of 3 layers, 64 tokens x 48 float4
    for (int idx = tid; idx < 64 * 48; idx += 256) {
        int r = idx / 48, k4 = idx % 48;
        size_t rowbase = ((size_t)b * (Sn + 1) + (s0 + r + 1)) * Dn + k0 + 4 * k4;
        float4 v0 = *(const float4*)(hid + rowbase);
        float4 v1 = *(const float4*)(hid + (size_t)Bn * (Sn + 1) * Dn + rowbase);
        float4 v2 = *(const float4*)(hid + (size_t)2 * Bn * (Sn + 1) * Dn + rowbase);
        float4 v;
        v.x = v0.x + v1.x + v2.x; v.y = v0.y + v1.y + v2.y;
        v.z = v0.z + v1.z + v2.z; v.w = v0.w + v1.w + v2.w;
        *(float4*)(xl + r * XSTR + 4 * k4) = v;
    }

    int tg = tid >> 4;  // 0..15 -> tokens tg*4..tg*4+3
    int rg = tid & 15;  // 0..15 -> co-rows rg*5..rg*5+4
    float acc[4][5];
#pragma unroll
    for (int tt = 0; tt < 4; ++tt)
#pragma unroll
        for (int rr = 0; rr < 5; ++rr) acc[tt][rr] = 0.f;

    for (int c = 0; c < 3; ++c) { // three 64-k chunks
        __syncthreads(); // also protects wl from previous chunk's readers
        for (int idx = tid; idx < 80 * 16; idx += 256) {
            int co = idx >> 4, k4c = idx & 15;
            int dir = co / 40, off = co % 40;
            int j = off >> 2, g = off & 3;
            const float* src = (dir ? Wb : Wf) + (g * 10 + j) * Dn + k0 + c * 64 + 4 * k4c;
            *(float4*)(wl + co * WSTR + 4 * k4c) = *(const float4*)src;
        }
        __syncthreads();
#pragma unroll 2
        for (int k4c = 0; k4c < 16; ++k4c) {
            float4 xv[4], wv[5];
#pragma unroll
            for (int tt = 0; tt < 4; ++tt)
                xv[tt] = *(const float4*)(xl + (tg * 4 + tt) * XSTR + c * 64 + 4 * k4c);
#pragma unroll
            for (int rr = 0; rr < 5; ++rr)
                wv[rr] = *(const float4*)(wl + (rg * 5 + rr) * WSTR + 4 * k4c);
#pragma unroll
            for (int tt = 0; tt < 4; ++tt)
#pragma unroll
                for (int rr = 0; rr < 5; ++rr) {
                    acc[tt][rr] += xv[tt].x * wv[rr].x + xv[tt].y * wv[rr].y
                                 + xv[tt].z * wv[rr].z + xv[tt].w * wv[rr].w;
                }
        }
    }
    size_t nbase = (size_t)kq * (Bn * Sn) + (size_t)b * Sn + s0;
#pragma unroll
    for (int tt = 0; tt < 4; ++tt) {
        size_t ob = (nbase + tg * 4 + tt) * 80 + rg * 5;
#pragma unroll
        for (int rr = 0; rr < 5; ++rr) tokg4[ob + rr] = acc[tt][rr];
    }
}

// ---------------- segment-mean in gate space (+ sum of 4 K-partials) + bias -> xg ----------------
__global__ __launch_bounds__(128) void k_wordmean(const float* __restrict__ tokg4,
                                                  const int* __restrict__ cnt,
                                                  const int* __restrict__ lists,
                                                  const float* __restrict__ bih_f,
                                                  const float* __restrict__ bih_b,
                                                  float* __restrict__ xg) {
    const size_t NT80 = (size_t)Bn * Sn * 80;
    int bw = blockIdx.x; // b*Wn + w
    int b = bw / Wn, w = bw % Wn;
    int l = threadIdx.x;
    if (l >= 80) return;
    int dir = l / 40, off = l % 40;
    int c = cnt[bw];
    int cc = c < CAP ? c : CAP;
    float acc = 0.f;
    for (int tk = 0; tk < cc; ++tk) {
        int s = lists[bw * CAP + tk];
        size_t base = ((size_t)b * Sn + s) * 80 + l;
        acc += tokg4[base] + tokg4[base + NT80]
             + tokg4[base + 2 * NT80] + tokg4[base + 3 * NT80];
    }
    float inv = 1.0f / (3.0f * (float)(c > 0 ? c : 1));
    int brow = (off & 3) * 10 + (off >> 2); // gate*10 + j
    float bias = (dir ? bih_b : bih_f)[brow];
    xg[((size_t)(dir * Bn + b) * Wn + w) * 40 + off] = acc * inv + bias;
}

// ---------------- LSTM scan: 1 seq/wave, readlane h-broadcast, DPP gate combine ----------------
__global__ __launch_bounds__(64) void k_lstm(const float* __restrict__ xg,
                                             const float* __restrict__ Whh_f, const float* __restrict__ bhh_f,
                                             const float* __restrict__ Whh_b, const float* __restrict__ bhh_b,
                                             float* __restrict__ hs) {
    int lane = threadIdx.x;
    int seq = blockIdx.x;      // 0..63
    int dir = seq >> 5;
    int l = lane < 40 ? lane : 39;
    int j = l >> 2, G = l & 3;

    const float* Whh = dir ? Whh_b : Whh_f;
    const float* bhh = dir ? bhh_b : bhh_f;
    float wk[Hn];
#pragma unroll
    for (int k = 0; k < Hn; ++k) wk[k] = Whh[(G * Hn + j) * Hn + k];
    float bias = bhh[G * Hn + j];

    const float* xbase = xg + (size_t)seq * Wn * 40; // layout [t][j*4+gate]
    float* hbase = hs + (size_t)seq * Wn * Hn;
    bool st = (G == 0) && (lane < 40);

    float h = 0.f, c = 0.f;
    int dt = dir ? -1 : 1;
    int t = dir ? (Wn - 1) : 0;
    float xq[4];
    xq[0] = xbase[t * 40 + l];
    xq[1] = xbase[(t + dt) * 40 + l];
    xq[2] = xbase[(t + 2 * dt) * 40 + l];

#pragma unroll 4
    for (int step = 0; step < Wn; ++step) {
        float xv = xq[step & 3];
        xq[(step + 3) & 3] = xbase[(t + 3 * dt) * 40 + l]; // prefetch 3 ahead
        float hb[Hn];
#pragma unroll
        for (int k = 0; k < Hn; ++k) hb[k] = lane_bcast(h, 4 * k);
        float ga = xv, gb = bias;
#pragma unroll
        for (int k = 0; k < 5; ++k) ga += wk[k] * hb[k];
#pragma unroll
        for (int k = 5; k < Hn; ++k) gb += wk[k] * hb[k];
        float g = ga + gb;
        float gin = (G == 2) ? 2.f * g : g;
        float s = fsig(gin);
        float av = (G == 2) ? 2.f * s - 1.f : s;
        float ai = quad_bcast<0>(av);
        float af = quad_bcast<1>(av);
        float ag = quad_bcast<2>(av);
        float ao = quad_bcast<3>(av);
        c = af * c + ai * ag;
        h = ao * ftanh(c);
        if (st) hbase[t * Hn + j] = h;
        t += dt;
    }
}

// ---------------- MLP heads -> padded hpad[which][n][32] ----------------
__global__ __launch_bounds__(128) void k_mlp(const float* __restrict__ hs,
                                             const float* __restrict__ uW1, const float* __restrict__ ub1,
                                             const float* __restrict__ uW2, const float* __restrict__ ub2,
                                             const float* __restrict__ dW1, const float* __restrict__ db1,
                                             const float* __restrict__ dW2, const float* __restrict__ db2,
                                             float* __restrict__ hpad) {
    int bt = blockIdx.x; // b*Wn + t
    int b = bt / Wn, t = bt % Wn;
    __shared__ float x[20];
    int tid = threadIdx.x;
    if (tid < 20) {
        x[tid] = (tid < Hn) ? hs[((size_t)(0 * Bn + b) * Wn + t) * Hn + tid]
                            : hs[((size_t)(1 * Bn + b) * Wn + t) * Hn + (tid - Hn)];
    }
    __syncthreads();
    if (tid >= 124) { // pads for all 4 heads
        hpad[((size_t)(tid - 124) * Bn * Wn + bt) * 32 + 31] = 0.f;
        return;
    }
    int which = tid / 31, k = tid % 31;
    float v;
    if (k == 30) {
        v = 1.0f;
    } else {
        const float* Wm;
        const float* bv;
        if (which == 0) { Wm = uW1; bv = ub1; }
        else if (which == 1) { Wm = uW2; bv = ub2; }
        else if (which == 2) { Wm = dW1; bv = db1; }
        else { Wm = dW2; bv = db2; }
        float a = bv[k];
#pragma unroll
        for (int d = 0; d < 20; ++d) a += x[d] * Wm[d * BHn + k];
        v = a > 0.f ? a : 0.f;
    }
    hpad[((size_t)which * Bn * Wn + bt) * 32 + k] = v;
}

// ---------------- gather dr-h2 rows at j=head ----------------
__global__ __launch_bounds__(256) void k_gather(const float* __restrict__ hpad,
                                                const int* __restrict__ heads,
                                                float* __restrict__ h2g) {
    int idx = blockIdx.x * 256 + threadIdx.x; // n*8 + q
    int n = idx >> 3, q = idx & 7;
    int b = n >> 7;
    int jh = heads[n];
    if (jh < 0 || jh >= Wn) jh = 0;
    const float4* src = (const float4*)(hpad + ((size_t)3 * Bn * Wn + b * Wn + jh) * 32);
    ((float4*)(h2g + (size_t)n * 32))[q] = src[q];
}

// ---------------- deprel scores: thread=(n,o), U broadcast from LDS, h1/h2 in regs ----------------
__global__ __launch_bounds__(256) void k_drscore(const float* __restrict__ h1g,
                                                 const float* __restrict__ h2g,
                                                 const float* __restrict__ U, const float* __restrict__ dbias,
                                                 float* __restrict__ sc) {
    int nc = blockIdx.x & 63;
    int oq = blockIdx.x >> 6; // 0..12
    __shared__ float Ul[4][992]; // row stride 32 per h (aligned b128)
    int tid = threadIdx.x;
    for (int idx = tid; idx < 4 * 992; idx += 256) {
        int o = idx / 992, r = idx - o * 992;
        int h = r >> 5, g = r & 31;
        int oo = oq * 4 + o; if (oo >= Cn) oo = Cn - 1;
        Ul[o][r] = (g < 31) ? U[(size_t)oo * 961 + h * 31 + g] : 0.f;
    }
    int w = tid >> 6, lane = tid & 63;
    int o = oq * 4 + w;
    int n = nc * 64 + lane;
    float h2r[32];
    {
        const float4* p = (const float4*)(h2g + (size_t)n * 32);
#pragma unroll
        for (int q = 0; q < 8; ++q) {
            float4 v = p[q];
            h2r[4 * q + 0] = v.x; h2r[4 * q + 1] = v.y;
            h2r[4 * q + 2] = v.z; h2r[4 * q + 3] = v.w;
        }
    }
    float h1r[32];
    {
        const float4* p = (const float4*)(h1g + (size_t)n * 32);
#pragma unroll
        for (int q = 0; q < 8; ++q) {
            float4 v = p[q];
            h1r[4 * q + 0] = v.x; h1r[4 * q + 1] = v.y;
            h1r[4 * q + 2] = v.z; h1r[4 * q + 3] = v.w;
        }
    }
    __syncthreads();
    const float* up = Ul[w];
    float acc = 0.f;
    for (int h = 0; h < 31; ++h) {
        float t = 0.f;
#pragma unroll
        for (int g = 0; g < 32; ++g) t += up[h * 32 + g] * h2r[g];
        acc += h1r[h] * t;
    }
    if (o < Cn) sc[(size_t)n * Cn + o] = acc + dbias[o];
}

// ---------------- fused losses: one block per batch b ----------------
__global__ __launch_bounds__(256) void k_loss2(const float* __restrict__ hpad,
                                               const float* __restrict__ U0, const float* __restrict__ ubias,
                                               const float* __restrict__ sc,
                                               const int* __restrict__ heads,
                                               const unsigned char* __restrict__ masks,
                                               const int* __restrict__ dep_rels,
                                               float* __restrict__ out) {
    int b = blockIdx.x;
    int tid = threadIdx.x;
    __shared__ float h2s[128 * 36];
    __shared__ float tg[128 * 36];
    __shared__ float U0l[992];
    __shared__ float red[256];
    const float* h1a = hpad + (size_t)b * Wn * 32;                 // un h1 (padded)
    const float* h2a = hpad + ((size_t)Bn * Wn + b * Wn) * 32;     // un h2 (padded)
    for (int idx = tid; idx < 128 * 32; idx += 256)
        h2s[(idx >> 5) * 36 + (idx & 31)] = h2a[idx];
    for (int idx = tid; idx < 992; idx += 256) {
        int g = idx & 31;
        U0l[idx] = (g < 31) ? U0[(idx >> 5) * 31 + g] : 0.f;
    }
    __syncthreads();
    {
        int l = tid & 31, ig = tid >> 5; // ig 0..7
        float ur[31];
#pragma unroll
        for (int h = 0; h < 31; ++h) ur[h] = U0l[h * 32 + l];
        for (int ii = 0; ii < 16; ++ii) {
            int i = ig * 16 + ii;
            const float4* hp = (const float4*)(h1a + (size_t)i * 32);
            float hr[32];
#pragma unroll
            for (int q = 0; q < 8; ++q) {
                float4 v = hp[q];
                hr[4 * q] = v.x; hr[4 * q + 1] = v.y; hr[4 * q + 2] = v.z; hr[4 * q + 3] = v.w;
            }
            float a = 0.f;
#pragma unroll
            for (int h = 0; h < 31; ++h) a += hr[h] * ur[h];
            tg[i * 36 + l] = a;
        }
    }
    __syncthreads();
    float acc = 0.f;
    {
        int jg = tid & 7, ig2 = tid >> 3; // ig2 0..31 -> 4 i's; jg -> 16 j's
        float ub = ubias[0];
        float4 tq[4][8];
#pragma unroll
        for (int ii = 0; ii < 4; ++ii) {
            const float4* tp = (const float4*)(tg + (ig2 * 4 + ii) * 36);
#pragma unroll
            for (int q = 0; q < 8; ++q) tq[ii][q] = tp[q];
        }
        float m[4], lsum[4], sh[4];
        int hd[4];
#pragma unroll
        for (int ii = 0; ii < 4; ++ii) {
            m[ii] = -3e38f; lsum[ii] = 0.f; sh[ii] = 0.f;
            hd[ii] = heads[b * Wn + ig2 * 4 + ii];
        }
        for (int jj = 0; jj < 16; ++jj) {
            int j = jg * 16 + jj;
            const float4* h2p = (const float4*)(h2s + j * 36);
            float4 hq[8];
#pragma unroll
            for (int q = 0; q < 8; ++q) hq[q] = h2p[q];
#pragma unroll
            for (int ii = 0; ii < 4; ++ii) {
                int i = ig2 * 4 + ii;
                float s = ub;
#pragma unroll
                for (int q = 0; q < 8; ++q) {
                    s += tq[ii][q].x * hq[q].x + tq[ii][q].y * hq[q].y
                       + tq[ii][q].z * hq[q].z + tq[ii][q].w * hq[q].w;
                }
                if (j == i) s = NEGV;
                float mn = fmaxf(m[ii], s);
                lsum[ii] = lsum[ii] * __expf(m[ii] - mn) + __expf(s - mn);
                m[ii] = mn;
                if (j == hd[ii]) sh[ii] = s;
            }
        }
#pragma unroll
        for (int ii = 0; ii < 4; ++ii) {
            float shv = (jg == (hd[ii] >> 4)) ? sh[ii] : 0.f;
            float mm = m[ii], ll = lsum[ii];
#pragma unroll
            for (int off = 1; off < 8; off <<= 1) {
                float m2 = __shfl_xor(mm, off);
                float l2 = __shfl_xor(ll, off);
                float mn = fmaxf(mm, m2);
                ll = ll * __expf(mm - mn) + l2 * __expf(m2 - mn);
                mm = mn;
                shv += __shfl_xor(shv, off);
            }
            if (jg == 0) {
                int i = ig2 * 4 + ii;
                if (i >= 1 && !masks[b * Wn + i])
                    acc += -(shv - (mm + __logf(ll)));
            }
        }
    }
    if (tid < 128) {
        int n = b * Wn + tid;
        int r = dep_rels[n];
        if (r != 0 && r < Cn) {
            const float* sp = sc + (size_t)n * Cn;
            float mm = sp[0];
            for (int o = 1; o < Cn; ++o) mm = fmaxf(mm, sp[o]);
            float e = 0.f;
            for (int o = 0; o < Cn; ++o) e += __expf(sp[o] - mm);
            acc += -(sp[r] - (mm + __logf(e)));
        }
    }
    red[tid] = acc;
    __syncthreads();
    for (int off = 128; off > 0; off >>= 1) {
        if (tid < off) red[tid] += red[tid + off];
        __syncthreads();
    }
    if (tid == 0) atomicAdd(out, red[0]);
}

extern "C" void kernel_launch(void* const* d_in, const int* in_sizes, int n_in,
                              void* d_out, int out_size, void* d_ws, size_t ws_size,
                              hipStream_t stream) {
    const float* hiddens = (const float*)d_in[0];
    const int* b2t = (const int*)d_in[1];
    const int* heads = (const int*)d_in[2];
    const int* dep_rels = (const int*)d_in[3];
    const unsigned char* masks = (const unsigned char*)d_in[4];
    const float* Wih_f = (const float*)d_in[6];
    const float* Whh_f = (const float*)d_in[7];
    const float* bih_f = (const float*)d_in[8];
    const float* bhh_f = (const float*)d_in[9];
    const float* Wih_b = (const float*)d_in[10];
    const float* Whh_b = (const float*)d_in[11];
    const float* bih_b = (const float*)d_in[12];
    const float* bhh_b = (const float*)d_in[13];
    const float* un_W1 = (const float*)d_in[14];
    const float* un_b1 = (const float*)d_in[15];
    const float* un_W2 = (const float*)d_in[16];
    const float* un_b2 = (const float*)d_in[17];
    const float* un_U  = (const float*)d_in[18];
    const float* un_bias = (const float*)d_in[19];
    const float* dr_W1 = (const float*)d_in[20];
    const float* dr_b1 = (const float*)d_in[21];
    const float* dr_W2 = (const float*)d_in[22];
    const float* dr_b2 = (const float*)d_in[23];
    const float* dr_U  = (const float*)d_in[24];
    const float* dr_bias = (const float*)d_in[25];

    char* p = (char*)d_ws;
    int* cnt = (int*)p;           p += (size_t)Bn * Wn * 4;
    int* lists = (int*)p;         p += (size_t)Bn * Wn * CAP * 4;
    float* tokg4 = (float*)p;     p += (size_t)4 * Bn * Sn * 80 * 4;
    float* xg = (float*)p;        p += (size_t)2 * Bn * Wn * 40 * 4;
    float* hs = (float*)p;        p += (size_t)2 * Bn * Wn * Hn * 4;
    float* hpad = (float*)p;      p += (size_t)4 * Bn * Wn * 32 * 4;
    float* h2g = (float*)p;       p += (size_t)Bn * Wn * 32 * 4;
    float* sc = (float*)p;        p += (size_t)Bn * Wn * Cn * 4;

    float* out = (float*)d_out;

    k_zero<<<(Bn * Wn + 255) / 256, 256, 0, stream>>>(cnt, out);
    k_lists<<<(Bn * Sn + 255) / 256, 256, 0, stream>>>(b2t, cnt, lists);
    k_tokproj<<<96 * 4, 256, 0, stream>>>(hiddens, Wih_f, Wih_b, tokg4);
    k_wordmean<<<Bn * Wn, 128, 0, stream>>>(tokg4, cnt, lists, bih_f, bih_b, xg);
    k_lstm<<<64, 64, 0, stream>>>(xg, Whh_f, bhh_f, Whh_b, bhh_b, hs);
    k_mlp<<<Bn * Wn, 128, 0, stream>>>(hs, un_W1, un_b1, un_W2, un_b2,
                                       dr_W1, dr_b1, dr_W2, dr_b2, hpad);
    k_gather<<<Bn * Wn * 8 / 256, 256, 0, stream>>>(hpad, heads, h2g);
    k_drscore<<<13 * 64, 256, 0, stream>>>(hpad + (size_t)2 * Bn * Wn * 32, h2g, dr_U, dr_bias, sc);
    k_loss2<<<Bn, 256, 0, stream>>>(hpad, un_U, un_bias, sc, heads, masks, dep_rels, out);
}

// Round 10
// 100.864 us; speedup vs baseline: 2.0742x; 1.1532x over previous
//
#include <hip/hip_runtime.h>

#define Bn 32
#define Wn 128
#define Sn 192
#define Dn 768
#define Hn 10
#define BHn 30
#define Cn 50
#define CAP 8
#define NEGV -1e30f

__device__ __forceinline__ float fsig(float x) {
    return __builtin_amdgcn_rcpf(1.0f + __expf(-x));
}
__device__ __forceinline__ float ftanh(float x) {
    return 1.0f - 2.0f * __builtin_amdgcn_rcpf(1.0f + __expf(2.0f * x));
}
__device__ __forceinline__ float lane_bcast(float v, int srclane) {
    union { float f; int i; } u, w;
    u.f = v;
    w.i = __builtin_amdgcn_readlane(u.i, srclane);
    return w.f;
}
template <int Q>
__device__ __forceinline__ float quad_bcast(float v) {
    union { float f; int i; } u, w;
    u.f = v;
    w.i = __builtin_amdgcn_mov_dpp(u.i, (Q << 6) | (Q << 4) | (Q << 2) | Q, 0xf, 0xf, true);
    return w.f;
}

// ---------------- zero counters + output ----------------
__global__ void k_zero(int* cnt, float* out) {
    int i = blockIdx.x * blockDim.x + threadIdx.x;
    if (i < Bn * Wn) cnt[i] = 0;
    if (i == 0) out[0] = 0.f;
}

// ---------------- build token->word inverse lists ----------------
__global__ void k_lists(const int* __restrict__ b2t, int* cnt, int* lists) {
    int idx = blockIdx.x * blockDim.x + threadIdx.x;
    if (idx >= Bn * Sn) return;
    int b = idx / Sn;
    int w = b2t[idx];
    if (w < 0 || w >= Wn) return;
    int s = idx % Sn;
    int pos = atomicAdd(&cnt[b * Wn + w], 1);
    if (pos < CAP) lists[(b * Wn + w) * CAP + pos] = s;
}

// ---------------- token projection v4: LDS GEMM, 42KB LDS -> 3 blocks/CU ----------------
// block = 64 tokens x 80 rows x K-eighth(96); 256 threads; thread = 4 tok x 5 rows.
// tokg4[kq][n][co] partial, co = dir*40 + j*4 + gate
#define XSTR 100
#define WSTR 52
__global__ __launch_bounds__(256) void k_tokproj(const float* __restrict__ hid,
                                                 const float* __restrict__ Wf,
                                                 const float* __restrict__ Wb,
                                                 float* __restrict__ tokg4) {
    __shared__ float xl[64 * XSTR];  // 64 tokens x 96k (pad to 100) = 25.6KB
    __shared__ float wl[80 * WSTR];  // 80 co-rows x 48k (pad to 52) = 16.6KB
    int tb = blockIdx.x >> 3;
    int kq = blockIdx.x & 7;
    int b = tb / 3;
    int s0 = (tb % 3) * 64;
    int k0 = kq * 96;
    int tid = threadIdx.x;

    // stage x: sum of 3 layers, 64 tokens x 24 float4
    for (int idx = tid; idx < 64 * 24; idx += 256) {
        int r = idx / 24, k4 = idx % 24;
        size_t rowbase = ((size_t)b * (Sn + 1) + (s0 + r + 1)) * Dn + k0 + 4 * k4;
        float4 v0 = *(const float4*)(hid + rowbase);
        float4 v1 = *(const float4*)(hid + (size_t)Bn * (Sn + 1) * Dn + rowbase);
        float4 v2 = *(const float4*)(hid + (size_t)2 * Bn * (Sn + 1) * Dn + rowbase);
        float4 v;
        v.x = v0.x + v1.x + v2.x; v.y = v0.y + v1.y + v2.y;
        v.z = v0.z + v1.z + v2.z; v.w = v0.w + v1.w + v2.w;
        *(float4*)(xl + r * XSTR + 4 * k4) = v;
    }

    int tg = tid >> 4;  // 0..15 -> tokens tg*4..tg*4+3
    int rg = tid & 15;  // 0..15 -> co-rows rg*5..rg*5+4
    float acc[4][5];
#pragma unroll
    for (int tt = 0; tt < 4; ++tt)
#pragma unroll
        for (int rr = 0; rr < 5; ++rr) acc[tt][rr] = 0.f;

    for (int c = 0; c < 2; ++c) { // two 48-k chunks of W
        __syncthreads();
        for (int idx = tid; idx < 80 * 12; idx += 256) {
            int co = idx / 12, k4c = idx % 12;
            int dir = co / 40, off = co % 40;
            int j = off >> 2, g = off & 3;
            const float* src = (dir ? Wb : Wf) + (g * 10 + j) * Dn + k0 + c * 48 + 4 * k4c;
            *(float4*)(wl + co * WSTR + 4 * k4c) = *(const float4*)src;
        }
        __syncthreads();
#pragma unroll 2
        for (int k4c = 0; k4c < 12; ++k4c) {
            float4 xv[4], wv[5];
#pragma unroll
            for (int tt = 0; tt < 4; ++tt)
                xv[tt] = *(const float4*)(xl + (tg * 4 + tt) * XSTR + c * 48 + 4 * k4c);
#pragma unroll
            for (int rr = 0; rr < 5; ++rr)
                wv[rr] = *(const float4*)(wl + (rg * 5 + rr) * WSTR + 4 * k4c);
#pragma unroll
            for (int tt = 0; tt < 4; ++tt)
#pragma unroll
                for (int rr = 0; rr < 5; ++rr) {
                    acc[tt][rr] += xv[tt].x * wv[rr].x + xv[tt].y * wv[rr].y
                                 + xv[tt].z * wv[rr].z + xv[tt].w * wv[rr].w;
                }
        }
    }
    size_t nbase = (size_t)kq * (Bn * Sn) + (size_t)b * Sn + s0;
#pragma unroll
    for (int tt = 0; tt < 4; ++tt) {
        size_t ob = (nbase + tg * 4 + tt) * 80 + rg * 5;
#pragma unroll
        for (int rr = 0; rr < 5; ++rr) tokg4[ob + rr] = acc[tt][rr];
    }
}

// ---------------- segment-mean in gate space (+ sum of 8 K-partials) + bias -> xg ----------------
__global__ __launch_bounds__(128) void k_wordmean(const float* __restrict__ tokg4,
                                                  const int* __restrict__ cnt,
                                                  const int* __restrict__ lists,
                                                  const float* __restrict__ bih_f,
                                                  const float* __restrict__ bih_b,
                                                  float* __restrict__ xg) {
    const size_t NT80 = (size_t)Bn * Sn * 80;
    int bw = blockIdx.x; // b*Wn + w
    int b = bw / Wn, w = bw % Wn;
    int l = threadIdx.x;
    if (l >= 80) return;
    int dir = l / 40, off = l % 40;
    int c = cnt[bw];
    int cc = c < CAP ? c : CAP;
    float acc = 0.f;
    for (int tk = 0; tk < cc; ++tk) {
        int s = lists[bw * CAP + tk];
        size_t base = ((size_t)b * Sn + s) * 80 + l;
#pragma unroll
        for (int p = 0; p < 8; ++p) acc += tokg4[base + p * NT80];
    }
    float inv = 1.0f / (3.0f * (float)(c > 0 ? c : 1));
    int brow = (off & 3) * 10 + (off >> 2); // gate*10 + j
    float bias = (dir ? bih_b : bih_f)[brow];
    xg[((size_t)(dir * Bn + b) * Wn + w) * 40 + off] = acc * inv + bias;
}

// ---------------- LSTM scan: 1 seq/wave, readlane h-broadcast, DPP gate combine ----------------
__global__ __launch_bounds__(64) void k_lstm(const float* __restrict__ xg,
                                             const float* __restrict__ Whh_f, const float* __restrict__ bhh_f,
                                             const float* __restrict__ Whh_b, const float* __restrict__ bhh_b,
                                             float* __restrict__ hs) {
    int lane = threadIdx.x;
    int seq = blockIdx.x;      // 0..63
    int dir = seq >> 5;
    int l = lane < 40 ? lane : 39;
    int j = l >> 2, G = l & 3;

    const float* Whh = dir ? Whh_b : Whh_f;
    const float* bhh = dir ? bhh_b : bhh_f;
    float wk[Hn];
#pragma unroll
    for (int k = 0; k < Hn; ++k) wk[k] = Whh[(G * Hn + j) * Hn + k];
    float bias = bhh[G * Hn + j];

    const float* xbase = xg + (size_t)seq * Wn * 40; // layout [t][j*4+gate]
    float* hbase = hs + (size_t)seq * Wn * Hn;
    bool st = (G == 0) && (lane < 40);

    float h = 0.f, c = 0.f;
    int dt = dir ? -1 : 1;
    int t = dir ? (Wn - 1) : 0;
    float xq[4];
    xq[0] = xbase[t * 40 + l];
    xq[1] = xbase[(t + dt) * 40 + l];
    xq[2] = xbase[(t + 2 * dt) * 40 + l];

#pragma unroll 4
    for (int step = 0; step < Wn; ++step) {
        float xv = xq[step & 3];
        xq[(step + 3) & 3] = xbase[(t + 3 * dt) * 40 + l]; // prefetch 3 ahead
        float hb[Hn];
#pragma unroll
        for (int k = 0; k < Hn; ++k) hb[k] = lane_bcast(h, 4 * k);
        float ga = xv, gb = bias;
#pragma unroll
        for (int k = 0; k < 5; ++k) ga += wk[k] * hb[k];
#pragma unroll
        for (int k = 5; k < Hn; ++k) gb += wk[k] * hb[k];
        float g = ga + gb;
        float gin = (G == 2) ? 2.f * g : g;
        float s = fsig(gin);
        float av = (G == 2) ? 2.f * s - 1.f : s;
        float ai = quad_bcast<0>(av);
        float af = quad_bcast<1>(av);
        float ag = quad_bcast<2>(av);
        float ao = quad_bcast<3>(av);
        c = af * c + ai * ag;
        h = ao * ftanh(c);
        if (st) hbase[t * Hn + j] = h;
        t += dt;
    }
}

// ---------------- MLP heads -> padded hpad[which][n][32] ----------------
__global__ __launch_bounds__(128) void k_mlp(const float* __restrict__ hs,
                                             const float* __restrict__ uW1, const float* __restrict__ ub1,
                                             const float* __restrict__ uW2, const float* __restrict__ ub2,
                                             const float* __restrict__ dW1, const float* __restrict__ db1,
                                             const float* __restrict__ dW2, const float* __restrict__ db2,
                                             float* __restrict__ hpad) {
    int bt = blockIdx.x; // b*Wn + t
    int b = bt / Wn, t = bt % Wn;
    __shared__ float x[20];
    int tid = threadIdx.x;
    if (tid < 20) {
        x[tid] = (tid < Hn) ? hs[((size_t)(0 * Bn + b) * Wn + t) * Hn + tid]
                            : hs[((size_t)(1 * Bn + b) * Wn + t) * Hn + (tid - Hn)];
    }
    __syncthreads();
    if (tid >= 124) { // pads for all 4 heads
        hpad[((size_t)(tid - 124) * Bn * Wn + bt) * 32 + 31] = 0.f;
        return;
    }
    int which = tid / 31, k = tid % 31;
    float v;
    if (k == 30) {
        v = 1.0f;
    } else {
        const float* Wm;
        const float* bv;
        if (which == 0) { Wm = uW1; bv = ub1; }
        else if (which == 1) { Wm = uW2; bv = ub2; }
        else if (which == 2) { Wm = dW1; bv = db1; }
        else { Wm = dW2; bv = db2; }
        float a = bv[k];
#pragma unroll
        for (int d = 0; d < 20; ++d) a += x[d] * Wm[d * BHn + k];
        v = a > 0.f ? a : 0.f;
    }
    hpad[((size_t)which * Bn * Wn + bt) * 32 + k] = v;
}

// ---------------- gather dr-h2 rows at j=head ----------------
__global__ __launch_bounds__(256) void k_gather(const float* __restrict__ hpad,
                                                const int* __restrict__ heads,
                                                float* __restrict__ h2g) {
    int idx = blockIdx.x * 256 + threadIdx.x; // n*8 + q
    int n = idx >> 3, q = idx & 7;
    int b = n >> 7;
    int jh = heads[n];
    if (jh < 0 || jh >= Wn) jh = 0;
    const float4* src = (const float4*)(hpad + ((size_t)3 * Bn * Wn + b * Wn + jh) * 32);
    ((float4*)(h2g + (size_t)n * 32))[q] = src[q];
}

// ---------------- deprel scores: thread=(n,o), U broadcast from LDS, h1/h2 in regs ----------------
__global__ __launch_bounds__(256) void k_drscore(const float* __restrict__ h1g,
                                                 const float* __restrict__ h2g,
                                                 const float* __restrict__ U, const float* __restrict__ dbias,
                                                 float* __restrict__ sc) {
    int nc = blockIdx.x & 63;
    int oq = blockIdx.x >> 6; // 0..12
    __shared__ float Ul[4][992]; // row stride 32 per h (aligned b128)
    int tid = threadIdx.x;
    for (int idx = tid; idx < 4 * 992; idx += 256) {
        int o = idx / 992, r = idx - o * 992;
        int h = r >> 5, g = r & 31;
        int oo = oq * 4 + o; if (oo >= Cn) oo = Cn - 1;
        Ul[o][r] = (g < 31) ? U[(size_t)oo * 961 + h * 31 + g] : 0.f;
    }
    int w = tid >> 6, lane = tid & 63;
    int o = oq * 4 + w;
    int n = nc * 64 + lane;
    float h2r[32];
    {
        const float4* p = (const float4*)(h2g + (size_t)n * 32);
#pragma unroll
        for (int q = 0; q < 8; ++q) {
            float4 v = p[q];
            h2r[4 * q + 0] = v.x; h2r[4 * q + 1] = v.y;
            h2r[4 * q + 2] = v.z; h2r[4 * q + 3] = v.w;
        }
    }
    float h1r[32];
    {
        const float4* p = (const float4*)(h1g + (size_t)n * 32);
#pragma unroll
        for (int q = 0; q < 8; ++q) {
            float4 v = p[q];
            h1r[4 * q + 0] = v.x; h1r[4 * q + 1] = v.y;
            h1r[4 * q + 2] = v.z; h1r[4 * q + 3] = v.w;
        }
    }
    __syncthreads();
    const float* up = Ul[w];
    float acc = 0.f;
    for (int h = 0; h < 31; ++h) {
        float t = 0.f;
#pragma unroll
        for (int g = 0; g < 32; ++g) t += up[h * 32 + g] * h2r[g];
        acc += h1r[h] * t;
    }
    if (o < Cn) sc[(size_t)n * Cn + o] = acc + dbias[o];
}

// ---------------- fused losses: block = (b, i-chunk of 32); 128 blocks ----------------
__global__ __launch_bounds__(256) void k_loss2(const float* __restrict__ hpad,
                                               const float* __restrict__ U0, const float* __restrict__ ubias,
                                               const float* __restrict__ sc,
                                               const int* __restrict__ heads,
                                               const unsigned char* __restrict__ masks,
                                               const int* __restrict__ dep_rels,
                                               float* __restrict__ out) {
    int b = blockIdx.x >> 2;
    int ic = blockIdx.x & 3;
    int tid = threadIdx.x;
    __shared__ float h2s[128 * 36];
    __shared__ float tg[32 * 36];
    __shared__ float U0l[992];
    __shared__ float red[256];
    const float* h1a = hpad + (size_t)b * Wn * 32;                 // un h1 (padded)
    const float* h2a = hpad + ((size_t)Bn * Wn + b * Wn) * 32;     // un h2 (padded)
    for (int idx = tid; idx < 128 * 32; idx += 256)
        h2s[(idx >> 5) * 36 + (idx & 31)] = h2a[idx];
    for (int idx = tid; idx < 992; idx += 256) {
        int g = idx & 31;
        U0l[idx] = (g < 31) ? U0[(idx >> 5) * 31 + g] : 0.f;
    }
    __syncthreads();
    // tg[il][l] = sum_h h1[ic*32+il][h] * U0[h][l]
    {
        int l = tid & 31, ig = tid >> 5; // ig 0..7 -> 4 local rows each
        float ur[31];
#pragma unroll
        for (int h = 0; h < 31; ++h) ur[h] = U0l[h * 32 + l];
        for (int ii = 0; ii < 4; ++ii) {
            int il = ig * 4 + ii;
            int i = ic * 32 + il;
            const float4* hp = (const float4*)(h1a + (size_t)i * 32);
            float hr[32];
#pragma unroll
            for (int q = 0; q < 8; ++q) {
                float4 v = hp[q];
                hr[4 * q] = v.x; hr[4 * q + 1] = v.y; hr[4 * q + 2] = v.z; hr[4 * q + 3] = v.w;
            }
            float a = 0.f;
#pragma unroll
            for (int h = 0; h < 31; ++h) a += hr[h] * ur[h];
            tg[il * 36 + l] = a;
        }
    }
    __syncthreads();
    float acc = 0.f;
    {
        int jg = tid & 7, il = tid >> 3; // il 0..31, one i-row per thread
        int i = ic * 32 + il;
        float ub = ubias[0];
        float4 tq[8];
        const float4* tp = (const float4*)(tg + il * 36);
#pragma unroll
        for (int q = 0; q < 8; ++q) tq[q] = tp[q];
        float m = -3e38f, lsum = 0.f, sh = 0.f;
        int hd = heads[b * Wn + i];
        for (int jj = 0; jj < 16; ++jj) {
            int j = jg * 16 + ((jj + jg) & 15); // rotated: 8 jg-lanes hit 8 distinct bank groups
            const float4* h2p = (const float4*)(h2s + j * 36);
            float s = ub;
#pragma unroll
            for (int q = 0; q < 8; ++q) {
                float4 hq = h2p[q];
                s += tq[q].x * hq.x + tq[q].y * hq.y + tq[q].z * hq.z + tq[q].w * hq.w;
            }
            if (j == i) s = NEGV;
            float mn = fmaxf(m, s);
            lsum = lsum * __expf(m - mn) + __expf(s - mn);
            m = mn;
            if (j == hd) sh = s;
        }
        float shv = (jg == (hd >> 4)) ? sh : 0.f;
        float mm = m, ll = lsum;
#pragma unroll
        for (int off = 1; off < 8; off <<= 1) {
            float m2 = __shfl_xor(mm, off);
            float l2 = __shfl_xor(ll, off);
            float mn = fmaxf(mm, m2);
            ll = ll * __expf(mm - mn) + l2 * __expf(m2 - mn);
            mm = mn;
            shv += __shfl_xor(shv, off);
        }
        if (jg == 0 && i >= 1 && !masks[b * Wn + i])
            acc += -(shv - (mm + __logf(ll)));
    }
    // deprel CE for this block's 32 rows
    if (tid < 32) {
        int n = b * Wn + ic * 32 + tid;
        int r = dep_rels[n];
        if (r != 0 && r < Cn) {
            const float* sp = sc + (size_t)n * Cn;
            float mm = sp[0];
            for (int o = 1; o < Cn; ++o) mm = fmaxf(mm, sp[o]);
            float e = 0.f;
            for (int o = 0; o < Cn; ++o) e += __expf(sp[o] - mm);
            acc += -(sp[r] - (mm + __logf(e)));
        }
    }
    red[tid] = acc;
    __syncthreads();
    for (int off = 128; off > 0; off >>= 1) {
        if (tid < off) red[tid] += red[tid + off];
        __syncthreads();
    }
    if (tid == 0) atomicAdd(out, red[0]);
}

extern "C" void kernel_launch(void* const* d_in, const int* in_sizes, int n_in,
                              void* d_out, int out_size, void* d_ws, size_t ws_size,
                              hipStream_t stream) {
    const float* hiddens = (const float*)d_in[0];
    const int* b2t = (const int*)d_in[1];
    const int* heads = (const int*)d_in[2];
    const int* dep_rels = (const int*)d_in[3];
    const unsigned char* masks = (const unsigned char*)d_in[4];
    const float* Wih_f = (const float*)d_in[6];
    const float* Whh_f = (const float*)d_in[7];
    const float* bih_f = (const float*)d_in[8];
    const float* bhh_f = (const float*)d_in[9];
    const float* Wih_b = (const float*)d_in[10];
    const float* Whh_b = (const float*)d_in[11];
    const float* bih_b = (const float*)d_in[12];
    const float* bhh_b = (const float*)d_in[13];
    const float* un_W1 = (const float*)d_in[14];
    const float* un_b1 = (const float*)d_in[15];
    const float* un_W2 = (const float*)d_in[16];
    const float* un_b2 = (const float*)d_in[17];
    const float* un_U  = (const float*)d_in[18];
    const float* un_bias = (const float*)d_in[19];
    const float* dr_W1 = (const float*)d_in[20];
    const float* dr_b1 = (const float*)d_in[21];
    const float* dr_W2 = (const float*)d_in[22];
    const float* dr_b2 = (const float*)d_in[23];
    const float* dr_U  = (const float*)d_in[24];
    const float* dr_bias = (const float*)d_in[25];

    char* p = (char*)d_ws;
    int* cnt = (int*)p;           p += (size_t)Bn * Wn * 4;
    int* lists = (int*)p;         p += (size_t)Bn * Wn * CAP * 4;
    float* tokg4 = (float*)p;     p += (size_t)8 * Bn * Sn * 80 * 4;
    float* xg = (float*)p;        p += (size_t)2 * Bn * Wn * 40 * 4;
    float* hs = (float*)p;        p += (size_t)2 * Bn * Wn * Hn * 4;
    float* hpad = (float*)p;      p += (size_t)4 * Bn * Wn * 32 * 4;
    float* h2g = (float*)p;       p += (size_t)Bn * Wn * 32 * 4;
    float* sc = (float*)p;        p += (size_t)Bn * Wn * Cn * 4;

    float* out = (float*)d_out;

    k_zero<<<(Bn * Wn + 255) / 256, 256, 0, stream>>>(cnt, out);
    k_lists<<<(Bn * Sn + 255) / 256, 256, 0, stream>>>(b2t, cnt, lists);
    k_tokproj<<<96 * 8, 256, 0, stream>>>(hiddens, Wih_f, Wih_b, tokg4);
    k_wordmean<<<Bn * Wn, 128, 0, stream>>>(tokg4, cnt, lists, bih_f, bih_b, xg);
    k_lstm<<<64, 64, 0, stream>>>(xg, Whh_f, bhh_f, Whh_b, bhh_b, hs);
    k_mlp<<<Bn * Wn, 128, 0, stream>>>(hs, un_W1, un_b1, un_W2, un_b2,
                                       dr_W1, dr_b1, dr_W2, dr_b2, hpad);
    k_gather<<<Bn * Wn * 8 / 256, 256, 0, stream>>>(hpad, heads, h2g);
    k_drscore<<<13 * 64, 256, 0, stream>>>(hpad + (size_t)2 * Bn * Wn * 32, h2g, dr_U, dr_bias, sc);
    k_loss2<<<Bn * 4, 256, 0, stream>>>(hpad, un_U, un_bias, sc, heads, masks, dep_rels, out);
}